// Round 17
// baseline (285.562 us; speedup 1.0000x reference)
//
#include <hip/hip_runtime.h>

#define SC_L2E 0.180336880111120f  // 0.125 * log2(e)

typedef _Float16 half8v __attribute__((ext_vector_type(8)));
typedef _Float16 half4v __attribute__((ext_vector_type(4)));
typedef _Float16 half2v __attribute__((ext_vector_type(2)));
typedef float f32x4 __attribute__((ext_vector_type(4)));
typedef float f32x16 __attribute__((ext_vector_type(16)));

#if __has_builtin(__builtin_amdgcn_exp2f)
#define EXP2(x) __builtin_amdgcn_exp2f(x)
#else
#define EXP2(x) exp2f(x)
#endif

#if __has_builtin(__builtin_amdgcn_cvt_pkrtz)
#define CVTPK(a, b) __builtin_amdgcn_cvt_pkrtz((a), (b))
#else
static __device__ __forceinline__ half2v cvtpk_fb(float a, float b) {
  half2v h; h[0] = (_Float16)a; h[1] = (_Float16)b; return h;
}
#define CVTPK cvtpk_fb
#endif

#define FMAX3(a, b, c) fmaxf(fmaxf((a), (b)), (c))

// T2 swizzle for [row][32-half] tiles: chunk kc of row r at slot kc^((r>>1)&3).
#define SWZ_OFF(row, lg) ((row) * 32 + ((((lg) ^ (((row) >> 1) & 3))) * 8))

__device__ __forceinline__ void gload_lds16(const void* g, void* l) {
  __builtin_amdgcn_global_load_lds(
      (const __attribute__((address_space(1))) void*)g,
      (__attribute__((address_space(3))) void*)l, 16, 0, 0);
}

// ---------------------------------------------------------------------------
// Merged prep (ALL independent pre-GEMM work, one launch):
//   [0,2048)        weight fp32->fp16 cast (4 matrices)
//   [2048,18432)    text LayerNorm + fp16 cast
//   [18432,22528)   regions LayerNorm fp16 + raw fp16 (one pass)
//   [22528]         mask dtype detect
// ---------------------------------------------------------------------------
__global__ __launch_bounds__(256) void prep_all_kernel(
    const float* __restrict__ W0, const float* __restrict__ W1,
    const float* __restrict__ W2, const float* __restrict__ W3,
    _Float16* __restrict__ Wout, const float* __restrict__ text,
    const float* __restrict__ gq, const float* __restrict__ bq,
    _Float16* __restrict__ Tout, const float* __restrict__ regions,
    const float* __restrict__ gkv, const float* __restrict__ bkv,
    _Float16* __restrict__ Rln, _Float16* __restrict__ Rraw,
    const unsigned char* __restrict__ mask, int* __restrict__ flag) {
  const int blk = blockIdx.x;
  const int t = threadIdx.x;
  if (blk < 2048) {  // weights: 8 elems/thread
    const int i = blk * 256 + t;
    const int rgn = i >> 17;
    const float* W = (rgn == 0) ? W0 : (rgn == 1) ? W1 : (rgn == 2) ? W2 : W3;
    const int loc = i & 131071;
    const float4 a  = ((const float4*)W)[loc * 2];
    const float4 b2 = ((const float4*)W)[loc * 2 + 1];
    half8v y;
    y[0] = (_Float16)a.x;  y[1] = (_Float16)a.y;
    y[2] = (_Float16)a.z;  y[3] = (_Float16)a.w;
    y[4] = (_Float16)b2.x; y[5] = (_Float16)b2.y;
    y[6] = (_Float16)b2.z; y[7] = (_Float16)b2.w;
    ((half8v*)Wout)[i] = y;
  } else if (blk < 22528) {  // LayerNorm rows (text or regions)
    const bool is_text = blk < 18432;
    const int row = is_text ? (blk - 2048) : (blk - 18432);
    const float* X = is_text ? text : regions;
    const float* ga = is_text ? gq : gkv;
    const float* be = is_text ? bq : bkv;
    const float4 x = ((const float4*)(X + (size_t)row * 1024))[t];
    float s  = x.x + x.y + x.z + x.w;
    float ss = x.x * x.x + x.y * x.y + x.z * x.z + x.w * x.w;
#pragma unroll
    for (int off = 32; off > 0; off >>= 1) {
      s  += __shfl_down(s, off);
      ss += __shfl_down(ss, off);
    }
    __shared__ float red[8];
    __shared__ float smu, srs;
    if ((t & 63) == 0) { red[(t >> 6) * 2] = s; red[(t >> 6) * 2 + 1] = ss; }
    __syncthreads();
    if (t == 0) {
      const float S  = red[0] + red[2] + red[4] + red[6];
      const float SS = red[1] + red[3] + red[5] + red[7];
      const float mm = S * (1.f / 1024.f);
      const float vv = SS * (1.f / 1024.f) - mm * mm;
      smu = mm; srs = rsqrtf(vv + 1e-5f);
    }
    __syncthreads();
    const float mu = smu, rs = srs;
    const float4 g  = ((const float4*)ga)[t];
    const float4 bb = ((const float4*)be)[t];
    half4v y;
    y[0] = (_Float16)((x.x - mu) * rs * g.x + bb.x);
    y[1] = (_Float16)((x.y - mu) * rs * g.y + bb.y);
    y[2] = (_Float16)((x.z - mu) * rs * g.z + bb.z);
    y[3] = (_Float16)((x.w - mu) * rs * g.w + bb.w);
    if (is_text) {
      ((half4v*)(Tout + (size_t)row * 1024))[t] = y;
    } else {
      half4v yr;
      yr[0] = (_Float16)x.x; yr[1] = (_Float16)x.y;
      yr[2] = (_Float16)x.z; yr[3] = (_Float16)x.w;
      ((half4v*)(Rln + (size_t)row * 1024))[t] = y;
      ((half4v*)(Rraw + (size_t)row * 1024))[t] = yr;
    }
  } else {  // mask detect
    __shared__ int sany;
    if (t == 0) sany = 0;
    __syncthreads();
    int any = 0;
    for (int i = t; i < 8 * 512; i += 256)
      if ((i & 3) != 0 && mask[i] != 0) any = 1;
    if (any) sany = 1;
    __syncthreads();
    if (t == 0) *flag = sany;  // 1 => uint8, 0 => int32
  }
}

// ---------------------------------------------------------------------------
// MID GEMM for M=16384: 128x256 tile, 256 threads, 4 waves each 64x128
// (12 ds_read_b128 per 32 MFMA = 0.375 ratio). 2-buffer LDS (48 KB!) with
// double-barrier counted-vmcnt: vmcnt(6) -> bar -> compute(t) -> bar ->
// stage(t+2, buf t&1). Race-free: a buffer is overwritten only after the
// barrier ending its readers. Grid 512 wgs -> 2-3 blocks/CU co-resident;
// independent barrier groups overlap each other's stalls and epilogues
// (the 256^2/128KB version had 1 block/CU: occupancy 16.6%, MfmaUtil 22%).
// Bijective XCD swizzle (512%8==0). T2 source-swizzle. T5 setprio.
// EPI 0: fp16 out scaled by SC_L2E (q path). EPI 1: fp32 + resid + bias.
// ---------------------------------------------------------------------------
template <int EPI>
__global__ __launch_bounds__(256) void hgemm_mid(
    const _Float16* __restrict__ A, const _Float16* __restrict__ W,
    void* __restrict__ Yv, const float* __restrict__ bias,
    const float* __restrict__ resid) {
  __shared__ _Float16 As[8192];    // 2 bufs x [128][32]
  __shared__ _Float16 Bs[16384];   // 2 bufs x [256][32]
  const int tid = threadIdx.x;
  const int wg = blockIdx.x;                  // 512 wgs
  const int idx = wg >> 3;
  const int bm = (wg & 7) * 16 + (idx >> 2);  // XCD owns 16 consecutive bm
  const int bn = idx & 3;                     // bn fastest within XCD
  const int wid = tid >> 6, lane = tid & 63;
  const int wr = wid >> 1, wc = wid & 1;      // 2M x 2N waves, 64x128 each
  const int l15 = lane & 15, lg = lane >> 4;

  // A: 512 chunks/tile -> 2/thread.  B: 1024 chunks -> 4/thread.
  const int a0 = tid, a1 = tid + 256;
  const int sa0 = ((a0 & 3) ^ ((a0 >> 3) & 3)) * 8;
  const int sa1 = ((a1 & 3) ^ ((a1 >> 3) & 3)) * 8;
  const _Float16* Ag0 = A + (size_t)(bm * 128 + (a0 >> 2)) * 1024 + sa0;
  const _Float16* Ag1 = A + (size_t)(bm * 128 + (a1 >> 2)) * 1024 + sa1;
  const int b0 = tid, b1 = tid + 256, b2 = tid + 512, b3 = tid + 768;
  const int sb0 = ((b0 & 3) ^ ((b0 >> 3) & 3)) * 8;
  const int sb1 = ((b1 & 3) ^ ((b1 >> 3) & 3)) * 8;
  const int sb2 = ((b2 & 3) ^ ((b2 >> 3) & 3)) * 8;
  const int sb3 = ((b3 & 3) ^ ((b3 >> 3) & 3)) * 8;
  const _Float16* Bg0 = W + (size_t)(bn * 256 + (b0 >> 2)) * 1024 + sb0;
  const _Float16* Bg1 = W + (size_t)(bn * 256 + (b1 >> 2)) * 1024 + sb1;
  const _Float16* Bg2 = W + (size_t)(bn * 256 + (b2 >> 2)) * 1024 + sb2;
  const _Float16* Bg3 = W + (size_t)(bn * 256 + (b3 >> 2)) * 1024 + sb3;
  _Float16* Asl0 = &As[wid * 512];            // wave-uniform (+lane*16B HW)
  _Float16* Asl1 = &As[2048 + wid * 512];
  _Float16* Bsl0 = &Bs[wid * 512];
  _Float16* Bsl1 = &Bs[2048 + wid * 512];
  _Float16* Bsl2 = &Bs[4096 + wid * 512];
  _Float16* Bsl3 = &Bs[6144 + wid * 512];

  auto stage = [&](int tk, int bi) {
    const int off = tk * 32;
    gload_lds16(Ag0 + off, Asl0 + bi * 4096);
    gload_lds16(Ag1 + off, Asl1 + bi * 4096);
    gload_lds16(Bg0 + off, Bsl0 + bi * 8192);
    gload_lds16(Bg1 + off, Bsl1 + bi * 8192);
    gload_lds16(Bg2 + off, Bsl2 + bi * 8192);
    gload_lds16(Bg3 + off, Bsl3 + bi * 8192);
  };

  f32x4 acc[4][8] = {};
  auto compute = [&](int t) {
    const _Float16* Ab = &As[(t & 1) * 4096];
    const _Float16* Bb = &Bs[(t & 1) * 8192];
    half8v a[4], b[8];
#pragma unroll
    for (int m = 0; m < 4; m++) {
      const int row = wr * 64 + m * 16 + l15;
      a[m] = *(const half8v*)&Ab[SWZ_OFF(row, lg)];
    }
#pragma unroll
    for (int n = 0; n < 8; n++) {
      const int row = wc * 128 + n * 16 + l15;
      b[n] = *(const half8v*)&Bb[SWZ_OFF(row, lg)];
    }
    __builtin_amdgcn_s_setprio(1);
#pragma unroll
    for (int m = 0; m < 4; m++)
#pragma unroll
      for (int n = 0; n < 8; n++)
        acc[m][n] = __builtin_amdgcn_mfma_f32_16x16x32_f16(a[m], b[n], acc[m][n], 0, 0, 0);
    __builtin_amdgcn_s_setprio(0);
  };

  stage(0, 0);
  stage(1, 1);
  for (int t = 0; t < 30; ++t) {
    asm volatile("s_waitcnt vmcnt(6)" ::: "memory");  // tile t landed (mine)
    __builtin_amdgcn_sched_barrier(0);
    __builtin_amdgcn_s_barrier();                     // -> landed for ALL waves
    compute(t);
    __builtin_amdgcn_s_barrier();                     // all done reading buf t&1
    stage(t + 2, t & 1);                              // overwrite freed buffer
  }
  asm volatile("s_waitcnt vmcnt(6)" ::: "memory");
  __builtin_amdgcn_sched_barrier(0);
  __builtin_amdgcn_s_barrier();
  compute(30);
  asm volatile("s_waitcnt vmcnt(0)" ::: "memory");
  __builtin_amdgcn_sched_barrier(0);
  __builtin_amdgcn_s_barrier();
  compute(31);

  if (EPI == 0) {
    _Float16* Y = (_Float16*)Yv;
#pragma unroll
    for (int m = 0; m < 4; m++) {
      const int gr0 = bm * 128 + wr * 64 + m * 16 + lg * 4;
#pragma unroll
      for (int n = 0; n < 8; n++) {
        const int gc = bn * 256 + wc * 128 + n * 16 + l15;
#pragma unroll
        for (int r = 0; r < 4; r++)
          Y[(size_t)(gr0 + r) * 1024 + gc] = (_Float16)(acc[m][n][r] * SC_L2E);
      }
    }
  } else {
    float* Y = (float*)Yv;
#pragma unroll
    for (int m = 0; m < 4; m++) {
      const int gr0 = bm * 128 + wr * 64 + m * 16 + lg * 4;
#pragma unroll
      for (int n = 0; n < 8; n++) {
        const int gc = bn * 256 + wc * 128 + n * 16 + l15;
        const float bv = bias[gc];
#pragma unroll
        for (int r = 0; r < 4; r++)
          Y[(size_t)(gr0 + r) * 1024 + gc] =
              acc[m][n][r] + bv + resid[(size_t)(gr0 + r) * 1024 + gc];
      }
    }
  }
}

// ---------------------------------------------------------------------------
// Fused K and V projection GEMMs (unchanged: 128x128, 4-buf T4, T2, T5).
// z=0: LN(regions)@Wk -> k16 row-major; z=1: regions@Wv -> vT transposed.
// ---------------------------------------------------------------------------
__global__ __launch_bounds__(256) void hgemm_kv(
    const _Float16* __restrict__ Aln, const _Float16* __restrict__ Araw,
    const _Float16* __restrict__ Wk, const _Float16* __restrict__ Wv,
    _Float16* __restrict__ Yk, _Float16* __restrict__ YvT) {
  __shared__ _Float16 As[16384];
  __shared__ _Float16 Bs[16384];
  const int z = blockIdx.z;
  const _Float16* A = z ? Araw : Aln;
  const _Float16* W = z ? Wv : Wk;
  const int tid = threadIdx.x;
  const int bm = blockIdx.x, bn = blockIdx.y;
  const int wid = tid >> 6, lane = tid & 63;
  const int wr = wid >> 1, wc = wid & 1;
  const int l15 = lane & 15, lg = lane >> 4;

  const int c0 = tid, c1 = tid + 256;
  const int sc0 = ((c0 & 3) ^ ((c0 >> 3) & 3)) * 8;
  const int sc1 = ((c1 & 3) ^ ((c1 >> 3) & 3)) * 8;
  const _Float16* Ag0 = A + (size_t)(bm * 128 + (c0 >> 2)) * 1024 + sc0;
  const _Float16* Ag1 = A + (size_t)(bm * 128 + (c1 >> 2)) * 1024 + sc1;
  const _Float16* Bg0 = W + (size_t)(bn * 128 + (c0 >> 2)) * 1024 + sc0;
  const _Float16* Bg1 = W + (size_t)(bn * 128 + (c1 >> 2)) * 1024 + sc1;
  _Float16* Asl = &As[wid * 512];
  _Float16* Bsl = &Bs[wid * 512];

  auto stage = [&](int tk, int bi) {
    const int off = tk * 32;
    gload_lds16(Ag0 + off, Asl + bi * 4096);
    gload_lds16(Ag1 + off, Asl + bi * 4096 + 2048);
    gload_lds16(Bg0 + off, Bsl + bi * 4096);
    gload_lds16(Bg1 + off, Bsl + bi * 4096 + 2048);
  };

  f32x4 acc[4][4] = {};
  auto compute = [&](int t) {
    const _Float16* Ab = &As[(t & 3) * 4096];
    const _Float16* Bb = &Bs[(t & 3) * 4096];
    half8v a[4], b[4];
#pragma unroll
    for (int m = 0; m < 4; m++) {
      const int row = wr * 64 + m * 16 + l15;
      a[m] = *(const half8v*)&Ab[SWZ_OFF(row, lg)];
    }
#pragma unroll
    for (int n = 0; n < 4; n++) {
      const int row = wc * 64 + n * 16 + l15;
      b[n] = *(const half8v*)&Bb[SWZ_OFF(row, lg)];
    }
    __builtin_amdgcn_s_setprio(1);
#pragma unroll
    for (int m = 0; m < 4; m++)
#pragma unroll
      for (int n = 0; n < 4; n++)
        acc[m][n] = __builtin_amdgcn_mfma_f32_16x16x32_f16(a[m], b[n], acc[m][n], 0, 0, 0);
    __builtin_amdgcn_s_setprio(0);
  };

  stage(0, 0);
  stage(1, 1);
  for (int t = 0; t < 30; ++t) {
    stage(t + 2, (t + 2) & 3);
    asm volatile("s_waitcnt vmcnt(8)" ::: "memory");
    __builtin_amdgcn_sched_barrier(0);
    __builtin_amdgcn_s_barrier();
    compute(t);
  }
  asm volatile("s_waitcnt vmcnt(4)" ::: "memory");
  __builtin_amdgcn_sched_barrier(0);
  __builtin_amdgcn_s_barrier();
  compute(30);
  asm volatile("s_waitcnt vmcnt(0)" ::: "memory");
  __builtin_amdgcn_sched_barrier(0);
  __builtin_amdgcn_s_barrier();
  compute(31);

  if (z == 0) {
#pragma unroll
    for (int m = 0; m < 4; m++) {
      const int gr0 = bm * 128 + wr * 64 + m * 16 + lg * 4;
#pragma unroll
      for (int n = 0; n < 4; n++) {
        const int gc = bn * 128 + wc * 64 + n * 16 + l15;
#pragma unroll
        for (int r = 0; r < 4; r++)
          Yk[(size_t)(gr0 + r) * 1024 + gc] = (_Float16)acc[m][n][r];
      }
    }
  } else {
#pragma unroll
    for (int m = 0; m < 4; m++) {
      const int gr0 = bm * 128 + wr * 64 + m * 16 + lg * 4;
#pragma unroll
      for (int n = 0; n < 4; n++) {
        const int gc = bn * 128 + wc * 64 + n * 16 + l15;
#pragma unroll
        for (int r = 0; r < 4; r++) {
          const int tokenv = gr0 + r;
          YvT[(size_t)((tokenv >> 9) * 1024 + gc) * 512 + (tokenv & 511)] =
              (_Float16)acc[m][n][r];
        }
      }
    }
  }
}

// ---------------------------------------------------------------------------
// MFMA flash attention v9 (unchanged from round 16): T1 XCD swizzle +
// mask-as-MFMA-C-input + pre-scaled Q; defer-max; permlane PV assembly.
// ---------------------------------------------------------------------------
__global__ __launch_bounds__(256, 4) void attn_v9(
    const _Float16* __restrict__ q, const _Float16* __restrict__ kk,
    const _Float16* __restrict__ vT, const void* __restrict__ maskp,
    const int* __restrict__ flag, _Float16* __restrict__ ctx) {
  __shared__ union SMem {
    struct { _Float16 K[2][2][2048]; _Float16 V[2][2][2048]; } s;  // 32 KB
    _Float16 Ot[4][2048];                                          // 16 KB
  } sm;
  __shared__ float Msk[512];

  const int bid = (blockIdx.x & 7) * 256 + (blockIdx.x >> 3);
  const int qt = bid & 15, hh = (bid >> 4) & 15, b = bid >> 8;
  const int tid = threadIdx.x;
  const int wid = tid >> 6, lane = tid & 63;
  const int l31 = lane & 31;
  const int hi  = lane >> 5;

  {
    const bool mu8 = (*flag != 0);
    const unsigned char* m8 = (const unsigned char*)maskp;
    const int* m32 = (const int*)maskp;
    for (int i = tid; i < 512; i += 256) {
      const bool mv = mu8 ? (m8[b * 512 + i] != 0) : (m32[b * 512 + i] != 0);
      Msk[i] = mv ? 0.f : -__builtin_inff();
    }
  }

  const _Float16* kb = kk + (size_t)b * 512 * 1024 + hh * 64;
  const _Float16* vb = vT + (size_t)(b * 1024 + hh * 64) * 512;

  const int krow = wid * 8 + (lane >> 3);
  const int kchk = (lane & 7) ^ ((lane >> 3) & 7);
  const _Float16* ksrc = kb + (size_t)krow * 1024 + kchk * 8;
  const int vrow = wid * 16 + (lane >> 2);
  const int vchk = (lane & 3) ^ ((lane >> 3) & 3);
  const _Float16* vsrc = vb + (size_t)vrow * 512 + vchk * 8;

  const int tok0 = b * 2048 + qt * 128 + wid * 32;
  half8v bq[4];
#pragma unroll
  for (int kg = 0; kg < 4; kg++)
    bq[kg] = *(const half8v*)(q + (size_t)(tok0 + l31) * 1024 + hh * 64 + kg * 16 + hi * 8);

  float m_s = -1e30f, l_s = 0.f;
  f32x16 ot0 = {}, ot1 = {};

  auto stage = [&](int step, int bi) {
#pragma unroll
    for (int sub = 0; sub < 2; sub++) {
      const int tile = step * 2 + sub;
      gload_lds16(ksrc + (size_t)tile * 32 * 1024, &sm.s.K[bi][sub][wid * 512]);
      gload_lds16(vsrc + tile * 32, &sm.s.V[bi][sub][wid * 512]);
    }
  };

  stage(0, 0);
  __syncthreads();  // drains vmcnt; also covers Msk writes

  int buf = 0;
  for (int step = 0; step < 8; step++) {
    if (step < 7) stage(step + 1, buf ^ 1);

#pragma unroll
    for (int sub = 0; sub < 2; sub++) {
      const int nt = step * 2 + sub;

      half8v ak[4];
#pragma unroll
      for (int kg = 0; kg < 4; kg++)
        ak[kg] = *(const half8v*)&sm.s.K[buf][sub][l31 * 64 + ((kg * 2 + hi) ^ (l31 & 7)) * 8];

      f32x16 st;
#pragma unroll
      for (int j = 0; j < 4; j++) {
        const float4 mk = *(const float4*)&Msk[nt * 32 + j * 8 + hi * 4];
        st[4 * j + 0] = mk.x;
        st[4 * j + 1] = mk.y;
        st[4 * j + 2] = mk.z;
        st[4 * j + 3] = mk.w;
      }
#pragma unroll
      for (int kg = 0; kg < 4; kg++)
        st = __builtin_amdgcn_mfma_f32_32x32x16_f16(ak[kg], bq[kg], st, 0, 0, 0);

      half8v av[2][2];
#pragma unroll
      for (int dv = 0; dv < 2; dv++)
#pragma unroll
        for (int kc = 0; kc < 2; kc++)
          av[dv][kc] = *(const half8v*)&sm.s.V[buf][sub][(dv * 32 + l31) * 32 +
                                                        ((kc * 2 + hi) ^ ((l31 >> 1) & 3)) * 8];

      const float t0 = FMAX3(st[0], st[1], st[2]);
      const float t1 = FMAX3(st[3], st[4], st[5]);
      const float t2 = FMAX3(st[6], st[7], st[8]);
      const float t3 = FMAX3(st[9], st[10], st[11]);
      const float t4 = FMAX3(st[12], st[13], st[14]);
      float tmax = fmaxf(FMAX3(t0, t1, t2), FMAX3(t3, t4, st[15]));
      tmax = fmaxf(tmax, __shfl_xor(tmax, 32, 64));

      if (__any(tmax > m_s + 8.f)) {
        const float mnew = fmaxf(m_s, tmax);
        const float corr = EXP2(m_s - mnew);
        m_s = mnew;
        l_s *= corr;
#pragma unroll
        for (int r = 0; r < 16; r++) { ot0[r] *= corr; ot1[r] *= corr; }
      }

      float p[16];
#pragma unroll
      for (int r = 0; r < 16; r++) p[r] = EXP2(st[r] - m_s);  // bounded by 2^8

      unsigned int pk[4][2];
#pragma unroll
      for (int j = 0; j < 4; j++)
#pragma unroll
        for (int pp = 0; pp < 2; pp++)
          pk[j][pp] = __builtin_bit_cast(
              unsigned int, CVTPK(p[4 * j + 2 * pp], p[4 * j + 2 * pp + 1]));

      {
#pragma unroll
        for (int r = 0; r < 8; r++) p[r] += p[r + 8];
#pragma unroll
        for (int r = 0; r < 4; r++) p[r] += p[r + 4];
        float ts = (p[0] + p[1]) + (p[2] + p[3]);
        ts += __shfl_xor(ts, 32, 64);
        l_s += ts;
      }

      half8v pb[2];
#pragma unroll
      for (int kc = 0; kc < 2; kc++) {
        unsigned int x0 = pk[2 * kc][0], x1 = pk[2 * kc][1];
        unsigned int y0 = pk[2 * kc + 1][0], y1 = pk[2 * kc + 1][1];
        asm("v_permlane32_swap_b32 %0, %1" : "+v"(x0), "+v"(y0));
        asm("v_permlane32_swap_b32 %0, %1" : "+v"(x1), "+v"(y1));
        uint4 u; u.x = x0; u.y = x1; u.z = y0; u.w = y1;
        pb[kc] = __builtin_bit_cast(half8v, u);
      }

      ot0 = __builtin_amdgcn_mfma_f32_32x32x16_f16(av[0][0], pb[0], ot0, 0, 0, 0);
      ot0 = __builtin_amdgcn_mfma_f32_32x32x16_f16(av[0][1], pb[1], ot0, 0, 0, 0);
      ot1 = __builtin_amdgcn_mfma_f32_32x32x16_f16(av[1][0], pb[0], ot1, 0, 0, 0);
      ot1 = __builtin_amdgcn_mfma_f32_32x32x16_f16(av[1][1], pb[1], ot1, 0, 0, 0);
    }

    __syncthreads();
    buf ^= 1;
  }

  const float inv = (l_s > 0.f) ? (1.f / l_s) : 0.f;
#pragma unroll
  for (int dv = 0; dv < 2; dv++) {
#pragma unroll
    for (int j = 0; j < 4; j++)
#pragma unroll
      for (int pp = 0; pp < 2; pp++) {
        const int r = 4 * j + 2 * pp;
        const float v0 = (dv ? ot1[r] : ot0[r]) * inv;
        const float v1 = (dv ? ot1[r + 1] : ot0[r + 1]) * inv;
        const int col = dv * 32 + 8 * j + 4 * hi + 2 * pp;
        const int pos = l31 * 64 + (col ^ (8 * (l31 & 7)));
        *(unsigned int*)&sm.Ot[wid][pos] = __builtin_bit_cast(unsigned int, CVTPK(v0, v1));
      }
  }
  __syncthreads();
#pragma unroll
  for (int qh = 0; qh < 2; qh++)
#pragma unroll
    for (int k2 = 0; k2 < 2; k2++) {
      const int qq = qh * 16 + (lane >> 2);
      const int c  = (lane & 3) * 8 + k2 * 32;
      const half8v val = *(const half8v*)&sm.Ot[wid][qq * 64 + (c ^ (8 * (qq & 7)))];
      *(half8v*)(ctx + (size_t)(tok0 + qq) * 1024 + hh * 64 + c) = val;
    }
}

// ---------------------------------------------------------------------------
extern "C" void kernel_launch(void* const* d_in, const int* in_sizes, int n_in,
                              void* d_out, int out_size, void* d_ws, size_t ws_size,
                              hipStream_t stream) {
  const float* text    = (const float*)d_in[0];
  const float* regions = (const float*)d_in[1];
  const void*  mask    = d_in[2];
  const float* Wq      = (const float*)d_in[3];
  const float* Wk      = (const float*)d_in[4];
  const float* Wv      = (const float*)d_in[5];
  const float* Wo      = (const float*)d_in[6];
  const float* bo      = (const float*)d_in[7];
  const float* gq      = (const float*)d_in[8];
  const float* bq      = (const float*)d_in[9];
  const float* gkv     = (const float*)d_in[10];
  const float* bkv     = (const float*)d_in[11];

  _Float16* ws16 = (_Float16*)d_ws;
  _Float16* wq16 = ws16;                   // 4 weights contiguous, 1M halves each
  _Float16* wk16 = wq16 + 1048576;
  _Float16* wv16 = wk16 + 1048576;
  _Float16* wo16 = wv16 + 1048576;
  _Float16* at16 = wo16 + 1048576;         // 16.7M (LN text)
  _Float16* q16  = at16 + 16777216;        // 16.7M (doubles as ctx)
  _Float16* k16  = q16 + 16777216;         // 4.2M
  _Float16* vTb  = k16 + 4194304;          // 4.2M  (V^T: [b*1024 + col][512])
  int* flag = (int*)(vTb + 4194304);
  _Float16* rln16  = (_Float16*)(flag + 16);   // 4.2M (regions LN)
  _Float16* rraw16 = rln16 + 4194304;          // 4.2M (regions raw)

  // ALL independent prep in one launch (22529 blocks)
  prep_all_kernel<<<22529, 256, 0, stream>>>(
      Wq, Wk, Wv, Wo, wq16, text, gq, bq, at16,
      regions, gkv, bkv, rln16, rraw16,
      (const unsigned char*)mask, flag);

  // q = (LN(text) @ Wq^T) * (0.125*log2e)  (scale folded into epilogue)
  hgemm_mid<0><<<512, 256, 0, stream>>>(at16, wq16, q16, nullptr, nullptr);

  // k = LN(regions) @ Wk^T ; vT = (regions @ Wv^T)^T  (fused, grid.z)
  hgemm_kv<<<dim3(32, 8, 2), 256, 0, stream>>>(rln16, rraw16, wk16, wv16, k16, vTb);

  // attention (ctx overwrites q16; block-private rows/cols)
  attn_v9<<<2048, 256, 0, stream>>>(q16, k16, vTb, mask, flag, q16);

  // out = text + ctx @ Wo^T + bo
  hgemm_mid<1><<<512, 256, 0, stream>>>(q16, wo16, d_out, bo, text);
}

// Round 18
// 207.226 us; speedup vs baseline: 1.3780x; 1.3780x over previous
//
#include <hip/hip_runtime.h>

#define SC_L2E 0.180336880111120f  // 0.125 * log2(e)

typedef _Float16 half8v __attribute__((ext_vector_type(8)));
typedef _Float16 half4v __attribute__((ext_vector_type(4)));
typedef _Float16 half2v __attribute__((ext_vector_type(2)));
typedef float f32x4 __attribute__((ext_vector_type(4)));
typedef float f32x16 __attribute__((ext_vector_type(16)));

#if __has_builtin(__builtin_amdgcn_exp2f)
#define EXP2(x) __builtin_amdgcn_exp2f(x)
#else
#define EXP2(x) exp2f(x)
#endif

#if __has_builtin(__builtin_amdgcn_cvt_pkrtz)
#define CVTPK(a, b) __builtin_amdgcn_cvt_pkrtz((a), (b))
#else
static __device__ __forceinline__ half2v cvtpk_fb(float a, float b) {
  half2v h; h[0] = (_Float16)a; h[1] = (_Float16)b; return h;
}
#define CVTPK cvtpk_fb
#endif

#define FMAX3(a, b, c) fmaxf(fmaxf((a), (b)), (c))

// T2 swizzle for [row][32-half] tiles: chunk kc of row r at slot kc^((r>>1)&3).
#define SWZ_OFF(row, lg) ((row) * 32 + ((((lg) ^ (((row) >> 1) & 3))) * 8))

__device__ __forceinline__ void gload_lds16(const void* g, void* l) {
  __builtin_amdgcn_global_load_lds(
      (const __attribute__((address_space(1))) void*)g,
      (__attribute__((address_space(3))) void*)l, 16, 0, 0);
}

// ---------------------------------------------------------------------------
// Merged prep (ALL independent pre-GEMM work, one launch):
//   [0,2048)        weight fp32->fp16 cast (4 matrices)
//   [2048,18432)    text LayerNorm + fp16 cast
//   [18432,22528)   regions LayerNorm fp16 + raw fp16 (one pass)
//   [22528]         mask dtype detect
// ---------------------------------------------------------------------------
__global__ __launch_bounds__(256) void prep_all_kernel(
    const float* __restrict__ W0, const float* __restrict__ W1,
    const float* __restrict__ W2, const float* __restrict__ W3,
    _Float16* __restrict__ Wout, const float* __restrict__ text,
    const float* __restrict__ gq, const float* __restrict__ bq,
    _Float16* __restrict__ Tout, const float* __restrict__ regions,
    const float* __restrict__ gkv, const float* __restrict__ bkv,
    _Float16* __restrict__ Rln, _Float16* __restrict__ Rraw,
    const unsigned char* __restrict__ mask, int* __restrict__ flag) {
  const int blk = blockIdx.x;
  const int t = threadIdx.x;
  if (blk < 2048) {  // weights: 8 elems/thread
    const int i = blk * 256 + t;
    const int rgn = i >> 17;
    const float* W = (rgn == 0) ? W0 : (rgn == 1) ? W1 : (rgn == 2) ? W2 : W3;
    const int loc = i & 131071;
    const float4 a  = ((const float4*)W)[loc * 2];
    const float4 b2 = ((const float4*)W)[loc * 2 + 1];
    half8v y;
    y[0] = (_Float16)a.x;  y[1] = (_Float16)a.y;
    y[2] = (_Float16)a.z;  y[3] = (_Float16)a.w;
    y[4] = (_Float16)b2.x; y[5] = (_Float16)b2.y;
    y[6] = (_Float16)b2.z; y[7] = (_Float16)b2.w;
    ((half8v*)Wout)[i] = y;
  } else if (blk < 22528) {  // LayerNorm rows (text or regions)
    const bool is_text = blk < 18432;
    const int row = is_text ? (blk - 2048) : (blk - 18432);
    const float* X = is_text ? text : regions;
    const float* ga = is_text ? gq : gkv;
    const float* be = is_text ? bq : bkv;
    const float4 x = ((const float4*)(X + (size_t)row * 1024))[t];
    float s  = x.x + x.y + x.z + x.w;
    float ss = x.x * x.x + x.y * x.y + x.z * x.z + x.w * x.w;
#pragma unroll
    for (int off = 32; off > 0; off >>= 1) {
      s  += __shfl_down(s, off);
      ss += __shfl_down(ss, off);
    }
    __shared__ float red[8];
    __shared__ float smu, srs;
    if ((t & 63) == 0) { red[(t >> 6) * 2] = s; red[(t >> 6) * 2 + 1] = ss; }
    __syncthreads();
    if (t == 0) {
      const float S  = red[0] + red[2] + red[4] + red[6];
      const float SS = red[1] + red[3] + red[5] + red[7];
      const float mm = S * (1.f / 1024.f);
      const float vv = SS * (1.f / 1024.f) - mm * mm;
      smu = mm; srs = rsqrtf(vv + 1e-5f);
    }
    __syncthreads();
    const float mu = smu, rs = srs;
    const float4 g  = ((const float4*)ga)[t];
    const float4 bb = ((const float4*)be)[t];
    half4v y;
    y[0] = (_Float16)((x.x - mu) * rs * g.x + bb.x);
    y[1] = (_Float16)((x.y - mu) * rs * g.y + bb.y);
    y[2] = (_Float16)((x.z - mu) * rs * g.z + bb.z);
    y[3] = (_Float16)((x.w - mu) * rs * g.w + bb.w);
    if (is_text) {
      ((half4v*)(Tout + (size_t)row * 1024))[t] = y;
    } else {
      half4v yr;
      yr[0] = (_Float16)x.x; yr[1] = (_Float16)x.y;
      yr[2] = (_Float16)x.z; yr[3] = (_Float16)x.w;
      ((half4v*)(Rln + (size_t)row * 1024))[t] = y;
      ((half4v*)(Rraw + (size_t)row * 1024))[t] = yr;
    }
  } else {  // mask detect
    __shared__ int sany;
    if (t == 0) sany = 0;
    __syncthreads();
    int any = 0;
    for (int i = t; i < 8 * 512; i += 256)
      if ((i & 3) != 0 && mask[i] != 0) any = 1;
    if (any) sany = 1;
    __syncthreads();
    if (t == 0) *flag = sany;  // 1 => uint8, 0 => int32
  }
}

// ---------------------------------------------------------------------------
// BIG GEMM for M=16384 shapes: 256x256 tile, 512 threads, 8 waves, T4
// counted-vmcnt pipeline (4 bufs, lookahead-2), T2 swizzle, XCD swizzle,
// T5 setprio.  (Round-17's 128x256/2-buf variant regressed 2x: pipeline
// depth collapsed + occupancy dropped — this 4-buf schedule is load-bearing.)
// EPI 0: fp16 out scaled by SC_L2E (q path: softmax scale*log2e folded here).
// EPI 1: fp32 out + resid + bias.
// ---------------------------------------------------------------------------
template <int EPI>
__global__ __launch_bounds__(512) void hgemm_big(
    const _Float16* __restrict__ A, const _Float16* __restrict__ W,
    void* __restrict__ Yv, const float* __restrict__ bias,
    const float* __restrict__ resid) {
  __shared__ _Float16 As[32768];  // 4 bufs x [256][32]
  __shared__ _Float16 Bs[32768];
  const int tid = threadIdx.x;
  const int wg = blockIdx.x;                 // 256 wgs
  const int bm = (wg & 7) * 8 + (wg >> 5);   // XCD owns 8 consecutive bm
  const int bn = (wg >> 3) & 3;              // bn fastest within XCD
  const int wid = tid >> 6, lane = tid & 63;
  const int wr = wid >> 2, wc = wid & 3;     // 2M x 4N waves
  const int l15 = lane & 15, lg = lane >> 4;

  const int c0 = tid, c1 = tid + 512;
  const int sc0 = ((c0 & 3) ^ ((c0 >> 3) & 3)) * 8;
  const int sc1 = ((c1 & 3) ^ ((c1 >> 3) & 3)) * 8;
  const _Float16* Ag0 = A + (size_t)(bm * 256 + (c0 >> 2)) * 1024 + sc0;
  const _Float16* Ag1 = A + (size_t)(bm * 256 + (c1 >> 2)) * 1024 + sc1;
  const _Float16* Bg0 = W + (size_t)(bn * 256 + (c0 >> 2)) * 1024 + sc0;
  const _Float16* Bg1 = W + (size_t)(bn * 256 + (c1 >> 2)) * 1024 + sc1;
  _Float16* Asl0 = &As[wid * 512];
  _Float16* Asl1 = &As[4096 + wid * 512];
  _Float16* Bsl0 = &Bs[wid * 512];
  _Float16* Bsl1 = &Bs[4096 + wid * 512];

  auto stage = [&](int tk, int bi) {
    const int off = tk * 32;
    gload_lds16(Ag0 + off, Asl0 + bi * 8192);
    gload_lds16(Ag1 + off, Asl1 + bi * 8192);
    gload_lds16(Bg0 + off, Bsl0 + bi * 8192);
    gload_lds16(Bg1 + off, Bsl1 + bi * 8192);
  };

  f32x4 acc[8][4] = {};
  auto compute = [&](int t) {
    const _Float16* Ab = &As[(t & 3) * 8192];
    const _Float16* Bb = &Bs[(t & 3) * 8192];
    half8v a[8], b[4];
#pragma unroll
    for (int m = 0; m < 8; m++) {
      const int row = wr * 128 + m * 16 + l15;
      a[m] = *(const half8v*)&Ab[SWZ_OFF(row, lg)];
    }
#pragma unroll
    for (int n = 0; n < 4; n++) {
      const int row = wc * 64 + n * 16 + l15;
      b[n] = *(const half8v*)&Bb[SWZ_OFF(row, lg)];
    }
    __builtin_amdgcn_s_setprio(1);
#pragma unroll
    for (int m = 0; m < 8; m++)
#pragma unroll
      for (int n = 0; n < 4; n++)
        acc[m][n] = __builtin_amdgcn_mfma_f32_16x16x32_f16(a[m], b[n], acc[m][n], 0, 0, 0);
    __builtin_amdgcn_s_setprio(0);
  };

  stage(0, 0);
  stage(1, 1);
  for (int t = 0; t < 30; ++t) {
    stage(t + 2, (t + 2) & 3);
    asm volatile("s_waitcnt vmcnt(8)" ::: "memory");
    __builtin_amdgcn_sched_barrier(0);
    __builtin_amdgcn_s_barrier();
    compute(t);
  }
  asm volatile("s_waitcnt vmcnt(4)" ::: "memory");
  __builtin_amdgcn_sched_barrier(0);
  __builtin_amdgcn_s_barrier();
  compute(30);
  asm volatile("s_waitcnt vmcnt(0)" ::: "memory");
  __builtin_amdgcn_sched_barrier(0);
  __builtin_amdgcn_s_barrier();
  compute(31);

  if (EPI == 0) {
    _Float16* Y = (_Float16*)Yv;
#pragma unroll
    for (int m = 0; m < 8; m++) {
      const int gr0 = bm * 256 + wr * 128 + m * 16 + lg * 4;
#pragma unroll
      for (int n = 0; n < 4; n++) {
        const int gc = bn * 256 + wc * 64 + n * 16 + l15;
#pragma unroll
        for (int r = 0; r < 4; r++)
          Y[(size_t)(gr0 + r) * 1024 + gc] = (_Float16)(acc[m][n][r] * SC_L2E);
      }
    }
  } else {
    float* Y = (float*)Yv;
#pragma unroll
    for (int m = 0; m < 8; m++) {
      const int gr0 = bm * 256 + wr * 128 + m * 16 + lg * 4;
#pragma unroll
      for (int n = 0; n < 4; n++) {
        const int gc = bn * 256 + wc * 64 + n * 16 + l15;
        const float bv = bias[gc];
#pragma unroll
        for (int r = 0; r < 4; r++)
          Y[(size_t)(gr0 + r) * 1024 + gc] =
              acc[m][n][r] + bv + resid[(size_t)(gr0 + r) * 1024 + gc];
      }
    }
  }
}

// ---------------------------------------------------------------------------
// Fused K and V projection GEMMs (T4 pipeline + T2 swizzle + T5 setprio).
// z=0: LN(regions)@Wk -> k16 row-major; z=1: regions@Wv -> vT transposed.
// ---------------------------------------------------------------------------
__global__ __launch_bounds__(256) void hgemm_kv(
    const _Float16* __restrict__ Aln, const _Float16* __restrict__ Araw,
    const _Float16* __restrict__ Wk, const _Float16* __restrict__ Wv,
    _Float16* __restrict__ Yk, _Float16* __restrict__ YvT) {
  __shared__ _Float16 As[16384];
  __shared__ _Float16 Bs[16384];
  const int z = blockIdx.z;
  const _Float16* A = z ? Araw : Aln;
  const _Float16* W = z ? Wv : Wk;
  const int tid = threadIdx.x;
  const int bm = blockIdx.x, bn = blockIdx.y;
  const int wid = tid >> 6, lane = tid & 63;
  const int wr = wid >> 1, wc = wid & 1;
  const int l15 = lane & 15, lg = lane >> 4;

  const int c0 = tid, c1 = tid + 256;
  const int sc0 = ((c0 & 3) ^ ((c0 >> 3) & 3)) * 8;
  const int sc1 = ((c1 & 3) ^ ((c1 >> 3) & 3)) * 8;
  const _Float16* Ag0 = A + (size_t)(bm * 128 + (c0 >> 2)) * 1024 + sc0;
  const _Float16* Ag1 = A + (size_t)(bm * 128 + (c1 >> 2)) * 1024 + sc1;
  const _Float16* Bg0 = W + (size_t)(bn * 128 + (c0 >> 2)) * 1024 + sc0;
  const _Float16* Bg1 = W + (size_t)(bn * 128 + (c1 >> 2)) * 1024 + sc1;
  _Float16* Asl = &As[wid * 512];
  _Float16* Bsl = &Bs[wid * 512];

  auto stage = [&](int tk, int bi) {
    const int off = tk * 32;
    gload_lds16(Ag0 + off, Asl + bi * 4096);
    gload_lds16(Ag1 + off, Asl + bi * 4096 + 2048);
    gload_lds16(Bg0 + off, Bsl + bi * 4096);
    gload_lds16(Bg1 + off, Bsl + bi * 4096 + 2048);
  };

  f32x4 acc[4][4] = {};
  auto compute = [&](int t) {
    const _Float16* Ab = &As[(t & 3) * 4096];
    const _Float16* Bb = &Bs[(t & 3) * 4096];
    half8v a[4], b[4];
#pragma unroll
    for (int m = 0; m < 4; m++) {
      const int row = wr * 64 + m * 16 + l15;
      a[m] = *(const half8v*)&Ab[SWZ_OFF(row, lg)];
    }
#pragma unroll
    for (int n = 0; n < 4; n++) {
      const int row = wc * 64 + n * 16 + l15;
      b[n] = *(const half8v*)&Bb[SWZ_OFF(row, lg)];
    }
    __builtin_amdgcn_s_setprio(1);
#pragma unroll
    for (int m = 0; m < 4; m++)
#pragma unroll
      for (int n = 0; n < 4; n++)
        acc[m][n] = __builtin_amdgcn_mfma_f32_16x16x32_f16(a[m], b[n], acc[m][n], 0, 0, 0);
    __builtin_amdgcn_s_setprio(0);
  };

  stage(0, 0);
  stage(1, 1);
  for (int t = 0; t < 30; ++t) {
    stage(t + 2, (t + 2) & 3);
    asm volatile("s_waitcnt vmcnt(8)" ::: "memory");
    __builtin_amdgcn_sched_barrier(0);
    __builtin_amdgcn_s_barrier();
    compute(t);
  }
  asm volatile("s_waitcnt vmcnt(4)" ::: "memory");
  __builtin_amdgcn_sched_barrier(0);
  __builtin_amdgcn_s_barrier();
  compute(30);
  asm volatile("s_waitcnt vmcnt(0)" ::: "memory");
  __builtin_amdgcn_sched_barrier(0);
  __builtin_amdgcn_s_barrier();
  compute(31);

  if (z == 0) {
#pragma unroll
    for (int m = 0; m < 4; m++) {
      const int gr0 = bm * 128 + wr * 64 + m * 16 + lg * 4;
#pragma unroll
      for (int n = 0; n < 4; n++) {
        const int gc = bn * 128 + wc * 64 + n * 16 + l15;
#pragma unroll
        for (int r = 0; r < 4; r++)
          Yk[(size_t)(gr0 + r) * 1024 + gc] = (_Float16)acc[m][n][r];
      }
    }
  } else {
#pragma unroll
    for (int m = 0; m < 4; m++) {
      const int gr0 = bm * 128 + wr * 64 + m * 16 + lg * 4;
#pragma unroll
      for (int n = 0; n < 4; n++) {
        const int gc = bn * 128 + wc * 64 + n * 16 + l15;
#pragma unroll
        for (int r = 0; r < 4; r++) {
          const int tokenv = gr0 + r;
          YvT[(size_t)((tokenv >> 9) * 1024 + gc) * 512 + (tokenv & 511)] =
              (_Float16)acc[m][n][r];
        }
      }
    }
  }
}

// ---------------------------------------------------------------------------
// MFMA flash attention v9: T1 XCD swizzle (XCD x owns batch b=x -> K/V 4MB
// fits private L2; FETCH 82->24MB) + mask-as-MFMA-C-input + pre-scaled Q
// (scale/mask fma pass eliminated); defer-max; permlane PV assembly;
// swizzled LDS epilogue transpose.
// ---------------------------------------------------------------------------
__global__ __launch_bounds__(256, 4) void attn_v9(
    const _Float16* __restrict__ q, const _Float16* __restrict__ kk,
    const _Float16* __restrict__ vT, const void* __restrict__ maskp,
    const int* __restrict__ flag, _Float16* __restrict__ ctx) {
  __shared__ union SMem {
    struct { _Float16 K[2][2][2048]; _Float16 V[2][2][2048]; } s;  // 32 KB
    _Float16 Ot[4][2048];                                          // 16 KB
  } sm;
  __shared__ float Msk[512];

  const int bid = (blockIdx.x & 7) * 256 + (blockIdx.x >> 3);
  const int qt = bid & 15, hh = (bid >> 4) & 15, b = bid >> 8;
  const int tid = threadIdx.x;
  const int wid = tid >> 6, lane = tid & 63;
  const int l31 = lane & 31;
  const int hi  = lane >> 5;

  {
    const bool mu8 = (*flag != 0);
    const unsigned char* m8 = (const unsigned char*)maskp;
    const int* m32 = (const int*)maskp;
    for (int i = tid; i < 512; i += 256) {
      const bool mv = mu8 ? (m8[b * 512 + i] != 0) : (m32[b * 512 + i] != 0);
      Msk[i] = mv ? 0.f : -__builtin_inff();
    }
  }

  const _Float16* kb = kk + (size_t)b * 512 * 1024 + hh * 64;
  const _Float16* vb = vT + (size_t)(b * 1024 + hh * 64) * 512;

  const int krow = wid * 8 + (lane >> 3);
  const int kchk = (lane & 7) ^ ((lane >> 3) & 7);
  const _Float16* ksrc = kb + (size_t)krow * 1024 + kchk * 8;
  const int vrow = wid * 16 + (lane >> 2);
  const int vchk = (lane & 3) ^ ((lane >> 3) & 3);
  const _Float16* vsrc = vb + (size_t)vrow * 512 + vchk * 8;

  const int tok0 = b * 2048 + qt * 128 + wid * 32;
  half8v bq[4];
#pragma unroll
  for (int kg = 0; kg < 4; kg++)
    bq[kg] = *(const half8v*)(q + (size_t)(tok0 + l31) * 1024 + hh * 64 + kg * 16 + hi * 8);

  float m_s = -1e30f, l_s = 0.f;
  f32x16 ot0 = {}, ot1 = {};

  auto stage = [&](int step, int bi) {
#pragma unroll
    for (int sub = 0; sub < 2; sub++) {
      const int tile = step * 2 + sub;
      gload_lds16(ksrc + (size_t)tile * 32 * 1024, &sm.s.K[bi][sub][wid * 512]);
      gload_lds16(vsrc + tile * 32, &sm.s.V[bi][sub][wid * 512]);
    }
  };

  stage(0, 0);
  __syncthreads();  // drains vmcnt; also covers Msk writes

  int buf = 0;
  for (int step = 0; step < 8; step++) {
    if (step < 7) stage(step + 1, buf ^ 1);

#pragma unroll
    for (int sub = 0; sub < 2; sub++) {
      const int nt = step * 2 + sub;

      half8v ak[4];
#pragma unroll
      for (int kg = 0; kg < 4; kg++)
        ak[kg] = *(const half8v*)&sm.s.K[buf][sub][l31 * 64 + ((kg * 2 + hi) ^ (l31 & 7)) * 8];

      f32x16 st;
#pragma unroll
      for (int j = 0; j < 4; j++) {
        const float4 mk = *(const float4*)&Msk[nt * 32 + j * 8 + hi * 4];
        st[4 * j + 0] = mk.x;
        st[4 * j + 1] = mk.y;
        st[4 * j + 2] = mk.z;
        st[4 * j + 3] = mk.w;
      }
#pragma unroll
      for (int kg = 0; kg < 4; kg++)
        st = __builtin_amdgcn_mfma_f32_32x32x16_f16(ak[kg], bq[kg], st, 0, 0, 0);

      half8v av[2][2];
#pragma unroll
      for (int dv = 0; dv < 2; dv++)
#pragma unroll
        for (int kc = 0; kc < 2; kc++)
          av[dv][kc] = *(const half8v*)&sm.s.V[buf][sub][(dv * 32 + l31) * 32 +
                                                        ((kc * 2 + hi) ^ ((l31 >> 1) & 3)) * 8];

      const float t0 = FMAX3(st[0], st[1], st[2]);
      const float t1 = FMAX3(st[3], st[4], st[5]);
      const float t2 = FMAX3(st[6], st[7], st[8]);
      const float t3 = FMAX3(st[9], st[10], st[11]);
      const float t4 = FMAX3(st[12], st[13], st[14]);
      float tmax = fmaxf(FMAX3(t0, t1, t2), FMAX3(t3, t4, st[15]));
      tmax = fmaxf(tmax, __shfl_xor(tmax, 32, 64));

      if (__any(tmax > m_s + 8.f)) {
        const float mnew = fmaxf(m_s, tmax);
        const float corr = EXP2(m_s - mnew);
        m_s = mnew;
        l_s *= corr;
#pragma unroll
        for (int r = 0; r < 16; r++) { ot0[r] *= corr; ot1[r] *= corr; }
      }

      float p[16];
#pragma unroll
      for (int r = 0; r < 16; r++) p[r] = EXP2(st[r] - m_s);  // bounded by 2^8

      unsigned int pk[4][2];
#pragma unroll
      for (int j = 0; j < 4; j++)
#pragma unroll
        for (int pp = 0; pp < 2; pp++)
          pk[j][pp] = __builtin_bit_cast(
              unsigned int, CVTPK(p[4 * j + 2 * pp], p[4 * j + 2 * pp + 1]));

      {
#pragma unroll
        for (int r = 0; r < 8; r++) p[r] += p[r + 8];
#pragma unroll
        for (int r = 0; r < 4; r++) p[r] += p[r + 4];
        float ts = (p[0] + p[1]) + (p[2] + p[3]);
        ts += __shfl_xor(ts, 32, 64);
        l_s += ts;
      }

      half8v pb[2];
#pragma unroll
      for (int kc = 0; kc < 2; kc++) {
        unsigned int x0 = pk[2 * kc][0], x1 = pk[2 * kc][1];
        unsigned int y0 = pk[2 * kc + 1][0], y1 = pk[2 * kc + 1][1];
        asm("v_permlane32_swap_b32 %0, %1" : "+v"(x0), "+v"(y0));
        asm("v_permlane32_swap_b32 %0, %1" : "+v"(x1), "+v"(y1));
        uint4 u; u.x = x0; u.y = x1; u.z = y0; u.w = y1;
        pb[kc] = __builtin_bit_cast(half8v, u);
      }

      ot0 = __builtin_amdgcn_mfma_f32_32x32x16_f16(av[0][0], pb[0], ot0, 0, 0, 0);
      ot0 = __builtin_amdgcn_mfma_f32_32x32x16_f16(av[0][1], pb[1], ot0, 0, 0, 0);
      ot1 = __builtin_amdgcn_mfma_f32_32x32x16_f16(av[1][0], pb[0], ot1, 0, 0, 0);
      ot1 = __builtin_amdgcn_mfma_f32_32x32x16_f16(av[1][1], pb[1], ot1, 0, 0, 0);
    }

    __syncthreads();
    buf ^= 1;
  }

  const float inv = (l_s > 0.f) ? (1.f / l_s) : 0.f;
#pragma unroll
  for (int dv = 0; dv < 2; dv++) {
#pragma unroll
    for (int j = 0; j < 4; j++)
#pragma unroll
      for (int pp = 0; pp < 2; pp++) {
        const int r = 4 * j + 2 * pp;
        const float v0 = (dv ? ot1[r] : ot0[r]) * inv;
        const float v1 = (dv ? ot1[r + 1] : ot0[r + 1]) * inv;
        const int col = dv * 32 + 8 * j + 4 * hi + 2 * pp;
        const int pos = l31 * 64 + (col ^ (8 * (l31 & 7)));
        *(unsigned int*)&sm.Ot[wid][pos] = __builtin_bit_cast(unsigned int, CVTPK(v0, v1));
      }
  }
  __syncthreads();
#pragma unroll
  for (int qh = 0; qh < 2; qh++)
#pragma unroll
    for (int k2 = 0; k2 < 2; k2++) {
      const int qq = qh * 16 + (lane >> 2);
      const int c  = (lane & 3) * 8 + k2 * 32;
      const half8v val = *(const half8v*)&sm.Ot[wid][qq * 64 + (c ^ (8 * (qq & 7)))];
      *(half8v*)(ctx + (size_t)(tok0 + qq) * 1024 + hh * 64 + c) = val;
    }
}

// ---------------------------------------------------------------------------
extern "C" void kernel_launch(void* const* d_in, const int* in_sizes, int n_in,
                              void* d_out, int out_size, void* d_ws, size_t ws_size,
                              hipStream_t stream) {
  const float* text    = (const float*)d_in[0];
  const float* regions = (const float*)d_in[1];
  const void*  mask    = d_in[2];
  const float* Wq      = (const float*)d_in[3];
  const float* Wk      = (const float*)d_in[4];
  const float* Wv      = (const float*)d_in[5];
  const float* Wo      = (const float*)d_in[6];
  const float* bo      = (const float*)d_in[7];
  const float* gq      = (const float*)d_in[8];
  const float* bq      = (const float*)d_in[9];
  const float* gkv     = (const float*)d_in[10];
  const float* bkv     = (const float*)d_in[11];

  _Float16* ws16 = (_Float16*)d_ws;
  _Float16* wq16 = ws16;                   // 4 weights contiguous, 1M halves each
  _Float16* wk16 = wq16 + 1048576;
  _Float16* wv16 = wk16 + 1048576;
  _Float16* wo16 = wv16 + 1048576;
  _Float16* at16 = wo16 + 1048576;         // 16.7M (LN text)
  _Float16* q16  = at16 + 16777216;        // 16.7M (doubles as ctx)
  _Float16* k16  = q16 + 16777216;         // 4.2M
  _Float16* vTb  = k16 + 4194304;          // 4.2M  (V^T: [b*1024 + col][512])
  int* flag = (int*)(vTb + 4194304);
  _Float16* rln16  = (_Float16*)(flag + 16);   // 4.2M (regions LN)
  _Float16* rraw16 = rln16 + 4194304;          // 4.2M (regions raw)

  // ALL independent prep in one launch (22529 blocks)
  prep_all_kernel<<<22529, 256, 0, stream>>>(
      Wq, Wk, Wv, Wo, wq16, text, gq, bq, at16,
      regions, gkv, bkv, rln16, rraw16,
      (const unsigned char*)mask, flag);

  // q = (LN(text) @ Wq^T) * (0.125*log2e)  (scale folded into epilogue)
  hgemm_big<0><<<256, 512, 0, stream>>>(at16, wq16, q16, nullptr, nullptr);

  // k = LN(regions) @ Wk^T ; vT = (regions @ Wv^T)^T  (fused, grid.z)
  hgemm_kv<<<dim3(32, 8, 2), 256, 0, stream>>>(rln16, rraw16, wk16, wv16, k16, vTb);

  // attention (ctx overwrites q16; block-private rows/cols)
  attn_v9<<<2048, 256, 0, stream>>>(q16, k16, vTb, mask, flag, q16);

  // out = text + ctx @ Wo^T + bo
  hgemm_big<1><<<256, 512, 0, stream>>>(q16, wo16, d_out, bo, text);
}

// Round 19
// 204.640 us; speedup vs baseline: 1.3954x; 1.0126x over previous
//
#include <hip/hip_runtime.h>

#define SC_L2E 0.180336880111120f  // 0.125 * log2(e)

typedef _Float16 half8v __attribute__((ext_vector_type(8)));
typedef _Float16 half4v __attribute__((ext_vector_type(4)));
typedef _Float16 half2v __attribute__((ext_vector_type(2)));
typedef float f32x4 __attribute__((ext_vector_type(4)));
typedef float f32x16 __attribute__((ext_vector_type(16)));

#if __has_builtin(__builtin_amdgcn_exp2f)
#define EXP2(x) __builtin_amdgcn_exp2f(x)
#else
#define EXP2(x) exp2f(x)
#endif

#if __has_builtin(__builtin_amdgcn_cvt_pkrtz)
#define CVTPK(a, b) __builtin_amdgcn_cvt_pkrtz((a), (b))
#else
static __device__ __forceinline__ half2v cvtpk_fb(float a, float b) {
  half2v h; h[0] = (_Float16)a; h[1] = (_Float16)b; return h;
}
#define CVTPK cvtpk_fb
#endif

#define FMAX3(a, b, c) fmaxf(fmaxf((a), (b)), (c))

// T2 swizzle for [row][32-half] tiles: chunk kc of row r at slot kc^((r>>1)&3).
#define SWZ_OFF(row, lg) ((row) * 32 + ((((lg) ^ (((row) >> 1) & 3))) * 8))

__device__ __forceinline__ void gload_lds16(const void* g, void* l) {
  __builtin_amdgcn_global_load_lds(
      (const __attribute__((address_space(1))) void*)g,
      (__attribute__((address_space(3))) void*)l, 16, 0, 0);
}

// ---------------------------------------------------------------------------
// Merged prep (ALL independent pre-GEMM work, one launch):
//   [0,2048)        weight fp32->fp16 cast (4 matrices)
//   [2048,18432)    text LayerNorm + fp16 cast
//   [18432,22528)   regions LayerNorm fp16 + raw fp16 (one pass)
//   [22528]         mask dtype detect
// ---------------------------------------------------------------------------
__global__ __launch_bounds__(256) void prep_all_kernel(
    const float* __restrict__ W0, const float* __restrict__ W1,
    const float* __restrict__ W2, const float* __restrict__ W3,
    _Float16* __restrict__ Wout, const float* __restrict__ text,
    const float* __restrict__ gq, const float* __restrict__ bq,
    _Float16* __restrict__ Tout, const float* __restrict__ regions,
    const float* __restrict__ gkv, const float* __restrict__ bkv,
    _Float16* __restrict__ Rln, _Float16* __restrict__ Rraw,
    const unsigned char* __restrict__ mask, int* __restrict__ flag) {
  const int blk = blockIdx.x;
  const int t = threadIdx.x;
  if (blk < 2048) {  // weights: 8 elems/thread
    const int i = blk * 256 + t;
    const int rgn = i >> 17;
    const float* W = (rgn == 0) ? W0 : (rgn == 1) ? W1 : (rgn == 2) ? W2 : W3;
    const int loc = i & 131071;
    const float4 a  = ((const float4*)W)[loc * 2];
    const float4 b2 = ((const float4*)W)[loc * 2 + 1];
    half8v y;
    y[0] = (_Float16)a.x;  y[1] = (_Float16)a.y;
    y[2] = (_Float16)a.z;  y[3] = (_Float16)a.w;
    y[4] = (_Float16)b2.x; y[5] = (_Float16)b2.y;
    y[6] = (_Float16)b2.z; y[7] = (_Float16)b2.w;
    ((half8v*)Wout)[i] = y;
  } else if (blk < 22528) {  // LayerNorm rows (text or regions)
    const bool is_text = blk < 18432;
    const int row = is_text ? (blk - 2048) : (blk - 18432);
    const float* X = is_text ? text : regions;
    const float* ga = is_text ? gq : gkv;
    const float* be = is_text ? bq : bkv;
    const float4 x = ((const float4*)(X + (size_t)row * 1024))[t];
    float s  = x.x + x.y + x.z + x.w;
    float ss = x.x * x.x + x.y * x.y + x.z * x.z + x.w * x.w;
#pragma unroll
    for (int off = 32; off > 0; off >>= 1) {
      s  += __shfl_down(s, off);
      ss += __shfl_down(ss, off);
    }
    __shared__ float red[8];
    __shared__ float smu, srs;
    if ((t & 63) == 0) { red[(t >> 6) * 2] = s; red[(t >> 6) * 2 + 1] = ss; }
    __syncthreads();
    if (t == 0) {
      const float S  = red[0] + red[2] + red[4] + red[6];
      const float SS = red[1] + red[3] + red[5] + red[7];
      const float mm = S * (1.f / 1024.f);
      const float vv = SS * (1.f / 1024.f) - mm * mm;
      smu = mm; srs = rsqrtf(vv + 1e-5f);
    }
    __syncthreads();
    const float mu = smu, rs = srs;
    const float4 g  = ((const float4*)ga)[t];
    const float4 bb = ((const float4*)be)[t];
    half4v y;
    y[0] = (_Float16)((x.x - mu) * rs * g.x + bb.x);
    y[1] = (_Float16)((x.y - mu) * rs * g.y + bb.y);
    y[2] = (_Float16)((x.z - mu) * rs * g.z + bb.z);
    y[3] = (_Float16)((x.w - mu) * rs * g.w + bb.w);
    if (is_text) {
      ((half4v*)(Tout + (size_t)row * 1024))[t] = y;
    } else {
      half4v yr;
      yr[0] = (_Float16)x.x; yr[1] = (_Float16)x.y;
      yr[2] = (_Float16)x.z; yr[3] = (_Float16)x.w;
      ((half4v*)(Rln + (size_t)row * 1024))[t] = y;
      ((half4v*)(Rraw + (size_t)row * 1024))[t] = yr;
    }
  } else {  // mask detect
    __shared__ int sany;
    if (t == 0) sany = 0;
    __syncthreads();
    int any = 0;
    for (int i = t; i < 8 * 512; i += 256)
      if ((i & 3) != 0 && mask[i] != 0) any = 1;
    if (any) sany = 1;
    __syncthreads();
    if (t == 0) *flag = sany;  // 1 => uint8, 0 => int32
  }
}

// ---------------------------------------------------------------------------
// BIG GEMM, 8-phase-style fine-interleaved schedule (m201/m196 pattern):
// 256x256 tile, BK=32, 512 threads, 8 waves (2M x 4N, 128x64 out each).
// 3-slot LDS ring (96 KB): tile T in slot T%3; stage 2 tiles ahead into slot
// (T+2)%3 — its last readers (tile T-1) completed lgkmcnt(0) before tile T's
// opening barrier -> write-after-read safe. Per tile: opener vmcnt(4)+barrier;
// phase0 {read b[4]+a[0..3] | stage A-halves of T+2 | lgkmcnt(0)+sched_barrier
// | 16 MFMA in setprio}; mid-barrier; phase1 {read a[4..7] | stage B-halves |
// pin | 16 MFMA}. Per-thread load order [Ah0,Ah1,Bh0,Bh1]/tile -> vmcnt(4)
// exactly gates tile T. Uniform control flow (no divergent barriers).
// EPI 0: fp16 out scaled by SC_L2E (q path). EPI 1: fp32 + resid + bias.
// ---------------------------------------------------------------------------
template <int EPI>
__global__ __launch_bounds__(512) void hgemm_big(
    const _Float16* __restrict__ A, const _Float16* __restrict__ W,
    void* __restrict__ Yv, const float* __restrict__ bias,
    const float* __restrict__ resid) {
  __shared__ _Float16 As[24576];  // 3 slots x [256][32]
  __shared__ _Float16 Bs[24576];
  const int tid = threadIdx.x;
  const int wg = blockIdx.x;                 // 256 wgs
  const int bm = (wg & 7) * 8 + (wg >> 5);   // XCD owns 8 consecutive bm
  const int bn = (wg >> 3) & 3;              // bn fastest within XCD
  const int wid = tid >> 6, lane = tid & 63;
  const int wr = wid >> 2, wc = wid & 3;     // 2M x 4N waves
  const int l15 = lane & 15, lg = lane >> 4;

  // Staging sources (pre-swizzled chunk): half-tile = 128 rows x 32 halves
  // = 512 chunks = 1 gload/thread. row_local = tid>>2, src chunk =
  // (tid&3)^((tid>>3)&3)  [key (row>>1)&3].
  const int sc = ((tid & 3) ^ ((tid >> 3) & 3)) * 8;
  const _Float16* aS0 = A + (size_t)(bm * 256 + (tid >> 2)) * 1024 + sc;
  const _Float16* aS1 = aS0 + (size_t)128 * 1024;
  const _Float16* bS0 = W + (size_t)(bn * 256 + (tid >> 2)) * 1024 + sc;
  const _Float16* bS1 = bS0 + (size_t)128 * 1024;

  auto stageA = [&](int Tt, int sl) {
    gload_lds16(aS0 + Tt * 32, &As[sl * 8192 + wid * 512]);
    gload_lds16(aS1 + Tt * 32, &As[sl * 8192 + 4096 + wid * 512]);
  };
  auto stageB = [&](int Tt, int sl) {
    gload_lds16(bS0 + Tt * 32, &Bs[sl * 8192 + wid * 512]);
    gload_lds16(bS1 + Tt * 32, &Bs[sl * 8192 + 4096 + wid * 512]);
  };

  f32x4 acc[8][4] = {};

  // prologue: tiles 0 (slot 0) and 1 (slot 1); order [Ah0,Ah1,Bh0,Bh1]/tile
  stageA(0, 0); stageB(0, 0);
  stageA(1, 1); stageB(1, 1);

  int s = 0, s2 = 2;
  for (int T = 0; T < 32; ++T) {
    if (T < 31) {
      asm volatile("s_waitcnt vmcnt(4)" ::: "memory");  // tile T landed (mine)
    } else {
      asm volatile("s_waitcnt vmcnt(0)" ::: "memory");
    }
    __builtin_amdgcn_sched_barrier(0);
    __builtin_amdgcn_s_barrier();                       // landed for ALL waves
    const _Float16* Ab = &As[s * 8192];
    const _Float16* Bb = &Bs[s * 8192];

    // ---- phase 0: quadrant m 0..3 (needs b[0..3] too) ----
    half8v b0 = *(const half8v*)&Bb[SWZ_OFF(wc * 64 + 0 * 16 + l15, lg)];
    half8v b1 = *(const half8v*)&Bb[SWZ_OFF(wc * 64 + 1 * 16 + l15, lg)];
    half8v b2 = *(const half8v*)&Bb[SWZ_OFF(wc * 64 + 2 * 16 + l15, lg)];
    half8v b3 = *(const half8v*)&Bb[SWZ_OFF(wc * 64 + 3 * 16 + l15, lg)];
    half8v a0 = *(const half8v*)&Ab[SWZ_OFF(wr * 128 + 0 * 16 + l15, lg)];
    half8v a1 = *(const half8v*)&Ab[SWZ_OFF(wr * 128 + 1 * 16 + l15, lg)];
    half8v a2 = *(const half8v*)&Ab[SWZ_OFF(wr * 128 + 2 * 16 + l15, lg)];
    half8v a3 = *(const half8v*)&Ab[SWZ_OFF(wr * 128 + 3 * 16 + l15, lg)];
    if (T < 30) stageA(T + 2, s2);   // slot s2 free: tile T-1 readers done
    asm volatile("s_waitcnt lgkmcnt(0)" ::: "memory");
    __builtin_amdgcn_sched_barrier(0);
    __builtin_amdgcn_s_setprio(1);
    acc[0][0] = __builtin_amdgcn_mfma_f32_16x16x32_f16(a0, b0, acc[0][0], 0, 0, 0);
    acc[0][1] = __builtin_amdgcn_mfma_f32_16x16x32_f16(a0, b1, acc[0][1], 0, 0, 0);
    acc[0][2] = __builtin_amdgcn_mfma_f32_16x16x32_f16(a0, b2, acc[0][2], 0, 0, 0);
    acc[0][3] = __builtin_amdgcn_mfma_f32_16x16x32_f16(a0, b3, acc[0][3], 0, 0, 0);
    acc[1][0] = __builtin_amdgcn_mfma_f32_16x16x32_f16(a1, b0, acc[1][0], 0, 0, 0);
    acc[1][1] = __builtin_amdgcn_mfma_f32_16x16x32_f16(a1, b1, acc[1][1], 0, 0, 0);
    acc[1][2] = __builtin_amdgcn_mfma_f32_16x16x32_f16(a1, b2, acc[1][2], 0, 0, 0);
    acc[1][3] = __builtin_amdgcn_mfma_f32_16x16x32_f16(a1, b3, acc[1][3], 0, 0, 0);
    acc[2][0] = __builtin_amdgcn_mfma_f32_16x16x32_f16(a2, b0, acc[2][0], 0, 0, 0);
    acc[2][1] = __builtin_amdgcn_mfma_f32_16x16x32_f16(a2, b1, acc[2][1], 0, 0, 0);
    acc[2][2] = __builtin_amdgcn_mfma_f32_16x16x32_f16(a2, b2, acc[2][2], 0, 0, 0);
    acc[2][3] = __builtin_amdgcn_mfma_f32_16x16x32_f16(a2, b3, acc[2][3], 0, 0, 0);
    acc[3][0] = __builtin_amdgcn_mfma_f32_16x16x32_f16(a3, b0, acc[3][0], 0, 0, 0);
    acc[3][1] = __builtin_amdgcn_mfma_f32_16x16x32_f16(a3, b1, acc[3][1], 0, 0, 0);
    acc[3][2] = __builtin_amdgcn_mfma_f32_16x16x32_f16(a3, b2, acc[3][2], 0, 0, 0);
    acc[3][3] = __builtin_amdgcn_mfma_f32_16x16x32_f16(a3, b3, acc[3][3], 0, 0, 0);
    __builtin_amdgcn_s_setprio(0);
    __builtin_amdgcn_s_barrier();

    // ---- phase 1: quadrant m 4..7 (reuse b[0..3]) ----
    a0 = *(const half8v*)&Ab[SWZ_OFF(wr * 128 + 4 * 16 + l15, lg)];
    a1 = *(const half8v*)&Ab[SWZ_OFF(wr * 128 + 5 * 16 + l15, lg)];
    a2 = *(const half8v*)&Ab[SWZ_OFF(wr * 128 + 6 * 16 + l15, lg)];
    a3 = *(const half8v*)&Ab[SWZ_OFF(wr * 128 + 7 * 16 + l15, lg)];
    if (T < 30) stageB(T + 2, s2);
    asm volatile("s_waitcnt lgkmcnt(0)" ::: "memory");
    __builtin_amdgcn_sched_barrier(0);
    __builtin_amdgcn_s_setprio(1);
    acc[4][0] = __builtin_amdgcn_mfma_f32_16x16x32_f16(a0, b0, acc[4][0], 0, 0, 0);
    acc[4][1] = __builtin_amdgcn_mfma_f32_16x16x32_f16(a0, b1, acc[4][1], 0, 0, 0);
    acc[4][2] = __builtin_amdgcn_mfma_f32_16x16x32_f16(a0, b2, acc[4][2], 0, 0, 0);
    acc[4][3] = __builtin_amdgcn_mfma_f32_16x16x32_f16(a0, b3, acc[4][3], 0, 0, 0);
    acc[5][0] = __builtin_amdgcn_mfma_f32_16x16x32_f16(a1, b0, acc[5][0], 0, 0, 0);
    acc[5][1] = __builtin_amdgcn_mfma_f32_16x16x32_f16(a1, b1, acc[5][1], 0, 0, 0);
    acc[5][2] = __builtin_amdgcn_mfma_f32_16x16x32_f16(a1, b2, acc[5][2], 0, 0, 0);
    acc[5][3] = __builtin_amdgcn_mfma_f32_16x16x32_f16(a1, b3, acc[5][3], 0, 0, 0);
    acc[6][0] = __builtin_amdgcn_mfma_f32_16x16x32_f16(a2, b0, acc[6][0], 0, 0, 0);
    acc[6][1] = __builtin_amdgcn_mfma_f32_16x16x32_f16(a2, b1, acc[6][1], 0, 0, 0);
    acc[6][2] = __builtin_amdgcn_mfma_f32_16x16x32_f16(a2, b2, acc[6][2], 0, 0, 0);
    acc[6][3] = __builtin_amdgcn_mfma_f32_16x16x32_f16(a2, b3, acc[6][3], 0, 0, 0);
    acc[7][0] = __builtin_amdgcn_mfma_f32_16x16x32_f16(a3, b0, acc[7][0], 0, 0, 0);
    acc[7][1] = __builtin_amdgcn_mfma_f32_16x16x32_f16(a3, b1, acc[7][1], 0, 0, 0);
    acc[7][2] = __builtin_amdgcn_mfma_f32_16x16x32_f16(a3, b2, acc[7][2], 0, 0, 0);
    acc[7][3] = __builtin_amdgcn_mfma_f32_16x16x32_f16(a3, b3, acc[7][3], 0, 0, 0);
    __builtin_amdgcn_s_setprio(0);
    // no closing barrier: next tile's opener (vmcnt+s_barrier) seals readers

    s  = (s == 2)  ? 0 : s + 1;
    s2 = (s2 == 2) ? 0 : s2 + 1;
  }

  if (EPI == 0) {
    _Float16* Y = (_Float16*)Yv;
#pragma unroll
    for (int m = 0; m < 8; m++) {
      const int gr0 = bm * 256 + wr * 128 + m * 16 + lg * 4;
#pragma unroll
      for (int n = 0; n < 4; n++) {
        const int gc = bn * 256 + wc * 64 + n * 16 + l15;
#pragma unroll
        for (int r = 0; r < 4; r++)
          Y[(size_t)(gr0 + r) * 1024 + gc] = (_Float16)(acc[m][n][r] * SC_L2E);
      }
    }
  } else {
    float* Y = (float*)Yv;
#pragma unroll
    for (int m = 0; m < 8; m++) {
      const int gr0 = bm * 256 + wr * 128 + m * 16 + lg * 4;
#pragma unroll
      for (int n = 0; n < 4; n++) {
        const int gc = bn * 256 + wc * 64 + n * 16 + l15;
        const float bv = bias[gc];
#pragma unroll
        for (int r = 0; r < 4; r++)
          Y[(size_t)(gr0 + r) * 1024 + gc] =
              acc[m][n][r] + bv + resid[(size_t)(gr0 + r) * 1024 + gc];
      }
    }
  }
}

// ---------------------------------------------------------------------------
// Fused K and V projection GEMMs (T4 pipeline + T2 swizzle + T5 setprio).
// z=0: LN(regions)@Wk -> k16 row-major; z=1: regions@Wv -> vT transposed.
// ---------------------------------------------------------------------------
__global__ __launch_bounds__(256) void hgemm_kv(
    const _Float16* __restrict__ Aln, const _Float16* __restrict__ Araw,
    const _Float16* __restrict__ Wk, const _Float16* __restrict__ Wv,
    _Float16* __restrict__ Yk, _Float16* __restrict__ YvT) {
  __shared__ _Float16 As[16384];
  __shared__ _Float16 Bs[16384];
  const int z = blockIdx.z;
  const _Float16* A = z ? Araw : Aln;
  const _Float16* W = z ? Wv : Wk;
  const int tid = threadIdx.x;
  const int bm = blockIdx.x, bn = blockIdx.y;
  const int wid = tid >> 6, lane = tid & 63;
  const int wr = wid >> 1, wc = wid & 1;
  const int l15 = lane & 15, lg = lane >> 4;

  const int c0 = tid, c1 = tid + 256;
  const int sc0 = ((c0 & 3) ^ ((c0 >> 3) & 3)) * 8;
  const int sc1 = ((c1 & 3) ^ ((c1 >> 3) & 3)) * 8;
  const _Float16* Ag0 = A + (size_t)(bm * 128 + (c0 >> 2)) * 1024 + sc0;
  const _Float16* Ag1 = A + (size_t)(bm * 128 + (c1 >> 2)) * 1024 + sc1;
  const _Float16* Bg0 = W + (size_t)(bn * 128 + (c0 >> 2)) * 1024 + sc0;
  const _Float16* Bg1 = W + (size_t)(bn * 128 + (c1 >> 2)) * 1024 + sc1;
  _Float16* Asl = &As[wid * 512];
  _Float16* Bsl = &Bs[wid * 512];

  auto stage = [&](int tk, int bi) {
    const int off = tk * 32;
    gload_lds16(Ag0 + off, Asl + bi * 4096);
    gload_lds16(Ag1 + off, Asl + bi * 4096 + 2048);
    gload_lds16(Bg0 + off, Bsl + bi * 4096);
    gload_lds16(Bg1 + off, Bsl + bi * 4096 + 2048);
  };

  f32x4 acc[4][4] = {};
  auto compute = [&](int t) {
    const _Float16* Ab = &As[(t & 3) * 4096];
    const _Float16* Bb = &Bs[(t & 3) * 4096];
    half8v a[4], b[4];
#pragma unroll
    for (int m = 0; m < 4; m++) {
      const int row = wr * 64 + m * 16 + l15;
      a[m] = *(const half8v*)&Ab[SWZ_OFF(row, lg)];
    }
#pragma unroll
    for (int n = 0; n < 4; n++) {
      const int row = wc * 64 + n * 16 + l15;
      b[n] = *(const half8v*)&Bb[SWZ_OFF(row, lg)];
    }
    __builtin_amdgcn_s_setprio(1);
#pragma unroll
    for (int m = 0; m < 4; m++)
#pragma unroll
      for (int n = 0; n < 4; n++)
        acc[m][n] = __builtin_amdgcn_mfma_f32_16x16x32_f16(a[m], b[n], acc[m][n], 0, 0, 0);
    __builtin_amdgcn_s_setprio(0);
  };

  stage(0, 0);
  stage(1, 1);
  for (int t = 0; t < 30; ++t) {
    stage(t + 2, (t + 2) & 3);
    asm volatile("s_waitcnt vmcnt(8)" ::: "memory");
    __builtin_amdgcn_sched_barrier(0);
    __builtin_amdgcn_s_barrier();
    compute(t);
  }
  asm volatile("s_waitcnt vmcnt(4)" ::: "memory");
  __builtin_amdgcn_sched_barrier(0);
  __builtin_amdgcn_s_barrier();
  compute(30);
  asm volatile("s_waitcnt vmcnt(0)" ::: "memory");
  __builtin_amdgcn_sched_barrier(0);
  __builtin_amdgcn_s_barrier();
  compute(31);

  if (z == 0) {
#pragma unroll
    for (int m = 0; m < 4; m++) {
      const int gr0 = bm * 128 + wr * 64 + m * 16 + lg * 4;
#pragma unroll
      for (int n = 0; n < 4; n++) {
        const int gc = bn * 128 + wc * 64 + n * 16 + l15;
#pragma unroll
        for (int r = 0; r < 4; r++)
          Yk[(size_t)(gr0 + r) * 1024 + gc] = (_Float16)acc[m][n][r];
      }
    }
  } else {
#pragma unroll
    for (int m = 0; m < 4; m++) {
      const int gr0 = bm * 128 + wr * 64 + m * 16 + lg * 4;
#pragma unroll
      for (int n = 0; n < 4; n++) {
        const int gc = bn * 128 + wc * 64 + n * 16 + l15;
#pragma unroll
        for (int r = 0; r < 4; r++) {
          const int tokenv = gr0 + r;
          YvT[(size_t)((tokenv >> 9) * 1024 + gc) * 512 + (tokenv & 511)] =
              (_Float16)acc[m][n][r];
        }
      }
    }
  }
}

// ---------------------------------------------------------------------------
// MFMA flash attention v9 (frozen): T1 XCD swizzle + mask-as-MFMA-C-input +
// pre-scaled Q; defer-max; permlane PV assembly; swizzled LDS epilogue.
// ---------------------------------------------------------------------------
__global__ __launch_bounds__(256, 4) void attn_v9(
    const _Float16* __restrict__ q, const _Float16* __restrict__ kk,
    const _Float16* __restrict__ vT, const void* __restrict__ maskp,
    const int* __restrict__ flag, _Float16* __restrict__ ctx) {
  __shared__ union SMem {
    struct { _Float16 K[2][2][2048]; _Float16 V[2][2][2048]; } s;  // 32 KB
    _Float16 Ot[4][2048];                                          // 16 KB
  } sm;
  __shared__ float Msk[512];

  const int bid = (blockIdx.x & 7) * 256 + (blockIdx.x >> 3);
  const int qt = bid & 15, hh = (bid >> 4) & 15, b = bid >> 8;
  const int tid = threadIdx.x;
  const int wid = tid >> 6, lane = tid & 63;
  const int l31 = lane & 31;
  const int hi  = lane >> 5;

  {
    const bool mu8 = (*flag != 0);
    const unsigned char* m8 = (const unsigned char*)maskp;
    const int* m32 = (const int*)maskp;
    for (int i = tid; i < 512; i += 256) {
      const bool mv = mu8 ? (m8[b * 512 + i] != 0) : (m32[b * 512 + i] != 0);
      Msk[i] = mv ? 0.f : -__builtin_inff();
    }
  }

  const _Float16* kb = kk + (size_t)b * 512 * 1024 + hh * 64;
  const _Float16* vb = vT + (size_t)(b * 1024 + hh * 64) * 512;

  const int krow = wid * 8 + (lane >> 3);
  const int kchk = (lane & 7) ^ ((lane >> 3) & 7);
  const _Float16* ksrc = kb + (size_t)krow * 1024 + kchk * 8;
  const int vrow = wid * 16 + (lane >> 2);
  const int vchk = (lane & 3) ^ ((lane >> 3) & 3);
  const _Float16* vsrc = vb + (size_t)vrow * 512 + vchk * 8;

  const int tok0 = b * 2048 + qt * 128 + wid * 32;
  half8v bq[4];
#pragma unroll
  for (int kg = 0; kg < 4; kg++)
    bq[kg] = *(const half8v*)(q + (size_t)(tok0 + l31) * 1024 + hh * 64 + kg * 16 + hi * 8);

  float m_s = -1e30f, l_s = 0.f;
  f32x16 ot0 = {}, ot1 = {};

  auto stage = [&](int step, int bi) {
#pragma unroll
    for (int sub = 0; sub < 2; sub++) {
      const int tile = step * 2 + sub;
      gload_lds16(ksrc + (size_t)tile * 32 * 1024, &sm.s.K[bi][sub][wid * 512]);
      gload_lds16(vsrc + tile * 32, &sm.s.V[bi][sub][wid * 512]);
    }
  };

  stage(0, 0);
  __syncthreads();  // drains vmcnt; also covers Msk writes

  int buf = 0;
  for (int step = 0; step < 8; step++) {
    if (step < 7) stage(step + 1, buf ^ 1);

#pragma unroll
    for (int sub = 0; sub < 2; sub++) {
      const int nt = step * 2 + sub;

      half8v ak[4];
#pragma unroll
      for (int kg = 0; kg < 4; kg++)
        ak[kg] = *(const half8v*)&sm.s.K[buf][sub][l31 * 64 + ((kg * 2 + hi) ^ (l31 & 7)) * 8];

      f32x16 st;
#pragma unroll
      for (int j = 0; j < 4; j++) {
        const float4 mk = *(const float4*)&Msk[nt * 32 + j * 8 + hi * 4];
        st[4 * j + 0] = mk.x;
        st[4 * j + 1] = mk.y;
        st[4 * j + 2] = mk.z;
        st[4 * j + 3] = mk.w;
      }
#pragma unroll
      for (int kg = 0; kg < 4; kg++)
        st = __builtin_amdgcn_mfma_f32_32x32x16_f16(ak[kg], bq[kg], st, 0, 0, 0);

      half8v av[2][2];
#pragma unroll
      for (int dv = 0; dv < 2; dv++)
#pragma unroll
        for (int kc = 0; kc < 2; kc++)
          av[dv][kc] = *(const half8v*)&sm.s.V[buf][sub][(dv * 32 + l31) * 32 +
                                                        ((kc * 2 + hi) ^ ((l31 >> 1) & 3)) * 8];

      const float t0 = FMAX3(st[0], st[1], st[2]);
      const float t1 = FMAX3(st[3], st[4], st[5]);
      const float t2 = FMAX3(st[6], st[7], st[8]);
      const float t3 = FMAX3(st[9], st[10], st[11]);
      const float t4 = FMAX3(st[12], st[13], st[14]);
      float tmax = fmaxf(FMAX3(t0, t1, t2), FMAX3(t3, t4, st[15]));
      tmax = fmaxf(tmax, __shfl_xor(tmax, 32, 64));

      if (__any(tmax > m_s + 8.f)) {
        const float mnew = fmaxf(m_s, tmax);
        const float corr = EXP2(m_s - mnew);
        m_s = mnew;
        l_s *= corr;
#pragma unroll
        for (int r = 0; r < 16; r++) { ot0[r] *= corr; ot1[r] *= corr; }
      }

      float p[16];
#pragma unroll
      for (int r = 0; r < 16; r++) p[r] = EXP2(st[r] - m_s);  // bounded by 2^8

      unsigned int pk[4][2];
#pragma unroll
      for (int j = 0; j < 4; j++)
#pragma unroll
        for (int pp = 0; pp < 2; pp++)
          pk[j][pp] = __builtin_bit_cast(
              unsigned int, CVTPK(p[4 * j + 2 * pp], p[4 * j + 2 * pp + 1]));

      {
#pragma unroll
        for (int r = 0; r < 8; r++) p[r] += p[r + 8];
#pragma unroll
        for (int r = 0; r < 4; r++) p[r] += p[r + 4];
        float ts = (p[0] + p[1]) + (p[2] + p[3]);
        ts += __shfl_xor(ts, 32, 64);
        l_s += ts;
      }

      half8v pb[2];
#pragma unroll
      for (int kc = 0; kc < 2; kc++) {
        unsigned int x0 = pk[2 * kc][0], x1 = pk[2 * kc][1];
        unsigned int y0 = pk[2 * kc + 1][0], y1 = pk[2 * kc + 1][1];
        asm("v_permlane32_swap_b32 %0, %1" : "+v"(x0), "+v"(y0));
        asm("v_permlane32_swap_b32 %0, %1" : "+v"(x1), "+v"(y1));
        uint4 u; u.x = x0; u.y = x1; u.z = y0; u.w = y1;
        pb[kc] = __builtin_bit_cast(half8v, u);
      }

      ot0 = __builtin_amdgcn_mfma_f32_32x32x16_f16(av[0][0], pb[0], ot0, 0, 0, 0);
      ot0 = __builtin_amdgcn_mfma_f32_32x32x16_f16(av[0][1], pb[1], ot0, 0, 0, 0);
      ot1 = __builtin_amdgcn_mfma_f32_32x32x16_f16(av[1][0], pb[0], ot1, 0, 0, 0);
      ot1 = __builtin_amdgcn_mfma_f32_32x32x16_f16(av[1][1], pb[1], ot1, 0, 0, 0);
    }

    __syncthreads();
    buf ^= 1;
  }

  const float inv = (l_s > 0.f) ? (1.f / l_s) : 0.f;
#pragma unroll
  for (int dv = 0; dv < 2; dv++) {
#pragma unroll
    for (int j = 0; j < 4; j++)
#pragma unroll
      for (int pp = 0; pp < 2; pp++) {
        const int r = 4 * j + 2 * pp;
        const float v0 = (dv ? ot1[r] : ot0[r]) * inv;
        const float v1 = (dv ? ot1[r + 1] : ot0[r + 1]) * inv;
        const int col = dv * 32 + 8 * j + 4 * hi + 2 * pp;
        const int pos = l31 * 64 + (col ^ (8 * (l31 & 7)));
        *(unsigned int*)&sm.Ot[wid][pos] = __builtin_bit_cast(unsigned int, CVTPK(v0, v1));
      }
  }
  __syncthreads();
#pragma unroll
  for (int qh = 0; qh < 2; qh++)
#pragma unroll
    for (int k2 = 0; k2 < 2; k2++) {
      const int qq = qh * 16 + (lane >> 2);
      const int c  = (lane & 3) * 8 + k2 * 32;
      const half8v val = *(const half8v*)&sm.Ot[wid][qq * 64 + (c ^ (8 * (qq & 7)))];
      *(half8v*)(ctx + (size_t)(tok0 + qq) * 1024 + hh * 64 + c) = val;
    }
}

// ---------------------------------------------------------------------------
extern "C" void kernel_launch(void* const* d_in, const int* in_sizes, int n_in,
                              void* d_out, int out_size, void* d_ws, size_t ws_size,
                              hipStream_t stream) {
  const float* text    = (const float*)d_in[0];
  const float* regions = (const float*)d_in[1];
  const void*  mask    = d_in[2];
  const float* Wq      = (const float*)d_in[3];
  const float* Wk      = (const float*)d_in[4];
  const float* Wv      = (const float*)d_in[5];
  const float* Wo      = (const float*)d_in[6];
  const float* bo      = (const float*)d_in[7];
  const float* gq      = (const float*)d_in[8];
  const float* bq      = (const float*)d_in[9];
  const float* gkv     = (const float*)d_in[10];
  const float* bkv     = (const float*)d_in[11];

  _Float16* ws16 = (_Float16*)d_ws;
  _Float16* wq16 = ws16;                   // 4 weights contiguous, 1M halves each
  _Float16* wk16 = wq16 + 1048576;
  _Float16* wv16 = wk16 + 1048576;
  _Float16* wo16 = wv16 + 1048576;
  _Float16* at16 = wo16 + 1048576;         // 16.7M (LN text)
  _Float16* q16  = at16 + 16777216;        // 16.7M (doubles as ctx)
  _Float16* k16  = q16 + 16777216;         // 4.2M
  _Float16* vTb  = k16 + 4194304;          // 4.2M  (V^T: [b*1024 + col][512])
  int* flag = (int*)(vTb + 4194304);
  _Float16* rln16  = (_Float16*)(flag + 16);   // 4.2M (regions LN)
  _Float16* rraw16 = rln16 + 4194304;          // 4.2M (regions raw)

  // ALL independent prep in one launch (22529 blocks)
  prep_all_kernel<<<22529, 256, 0, stream>>>(
      Wq, Wk, Wv, Wo, wq16, text, gq, bq, at16,
      regions, gkv, bkv, rln16, rraw16,
      (const unsigned char*)mask, flag);

  // q = (LN(text) @ Wq^T) * (0.125*log2e)  (scale folded into epilogue)
  hgemm_big<0><<<256, 512, 0, stream>>>(at16, wq16, q16, nullptr, nullptr);

  // k = LN(regions) @ Wk^T ; vT = (regions @ Wv^T)^T  (fused, grid.z)
  hgemm_kv<<<dim3(32, 8, 2), 256, 0, stream>>>(rln16, rraw16, wk16, wv16, k16, vTb);

  // attention (ctx overwrites q16; block-private rows/cols)
  attn_v9<<<2048, 256, 0, stream>>>(q16, k16, vTb, mask, flag, q16);

  // out = text + ctx @ Wo^T + bo
  hgemm_big<1><<<256, 512, 0, stream>>>(q16, wo16, d_out, bo, text);
}

// Round 20
// 201.835 us; speedup vs baseline: 1.4148x; 1.0139x over previous
//
#include <hip/hip_runtime.h>

#define SC_L2E 0.180336880111120f  // 0.125 * log2(e)

typedef _Float16 half8v __attribute__((ext_vector_type(8)));
typedef _Float16 half4v __attribute__((ext_vector_type(4)));
typedef _Float16 half2v __attribute__((ext_vector_type(2)));
typedef float f32x4 __attribute__((ext_vector_type(4)));
typedef float f32x16 __attribute__((ext_vector_type(16)));

#if __has_builtin(__builtin_amdgcn_exp2f)
#define EXP2(x) __builtin_amdgcn_exp2f(x)
#else
#define EXP2(x) exp2f(x)
#endif

#if __has_builtin(__builtin_amdgcn_cvt_pkrtz)
#define CVTPK(a, b) __builtin_amdgcn_cvt_pkrtz((a), (b))
#else
static __device__ __forceinline__ half2v cvtpk_fb(float a, float b) {
  half2v h; h[0] = (_Float16)a; h[1] = (_Float16)b; return h;
}
#define CVTPK cvtpk_fb
#endif

#define FMAX3(a, b, c) fmaxf(fmaxf((a), (b)), (c))

// T2 swizzle for [row][32-half] tiles: chunk kc of row r at slot kc^((r>>1)&3).
#define SWZ_OFF(row, lg) ((row) * 32 + ((((lg) ^ (((row) >> 1) & 3))) * 8))

__device__ __forceinline__ void gload_lds16(const void* g, void* l) {
  __builtin_amdgcn_global_load_lds(
      (const __attribute__((address_space(1))) void*)g,
      (__attribute__((address_space(3))) void*)l, 16, 0, 0);
}

// ---------------------------------------------------------------------------
// Merged prep (ALL independent pre-GEMM work, one launch):
//   [0,2048)        weight fp32->fp16 cast (4 matrices)
//   [2048,18432)    text LayerNorm + fp16 cast
//   [18432,22528)   regions LayerNorm fp16 + raw fp16 (one pass)
//   [22528]         mask dtype detect
// ---------------------------------------------------------------------------
__global__ __launch_bounds__(256) void prep_all_kernel(
    const float* __restrict__ W0, const float* __restrict__ W1,
    const float* __restrict__ W2, const float* __restrict__ W3,
    _Float16* __restrict__ Wout, const float* __restrict__ text,
    const float* __restrict__ gq, const float* __restrict__ bq,
    _Float16* __restrict__ Tout, const float* __restrict__ regions,
    const float* __restrict__ gkv, const float* __restrict__ bkv,
    _Float16* __restrict__ Rln, _Float16* __restrict__ Rraw,
    const unsigned char* __restrict__ mask, int* __restrict__ flag) {
  const int blk = blockIdx.x;
  const int t = threadIdx.x;
  if (blk < 2048) {  // weights: 8 elems/thread
    const int i = blk * 256 + t;
    const int rgn = i >> 17;
    const float* W = (rgn == 0) ? W0 : (rgn == 1) ? W1 : (rgn == 2) ? W2 : W3;
    const int loc = i & 131071;
    const float4 a  = ((const float4*)W)[loc * 2];
    const float4 b2 = ((const float4*)W)[loc * 2 + 1];
    half8v y;
    y[0] = (_Float16)a.x;  y[1] = (_Float16)a.y;
    y[2] = (_Float16)a.z;  y[3] = (_Float16)a.w;
    y[4] = (_Float16)b2.x; y[5] = (_Float16)b2.y;
    y[6] = (_Float16)b2.z; y[7] = (_Float16)b2.w;
    ((half8v*)Wout)[i] = y;
  } else if (blk < 22528) {  // LayerNorm rows (text or regions)
    const bool is_text = blk < 18432;
    const int row = is_text ? (blk - 2048) : (blk - 18432);
    const float* X = is_text ? text : regions;
    const float* ga = is_text ? gq : gkv;
    const float* be = is_text ? bq : bkv;
    const float4 x = ((const float4*)(X + (size_t)row * 1024))[t];
    float s  = x.x + x.y + x.z + x.w;
    float ss = x.x * x.x + x.y * x.y + x.z * x.z + x.w * x.w;
#pragma unroll
    for (int off = 32; off > 0; off >>= 1) {
      s  += __shfl_down(s, off);
      ss += __shfl_down(ss, off);
    }
    __shared__ float red[8];
    __shared__ float smu, srs;
    if ((t & 63) == 0) { red[(t >> 6) * 2] = s; red[(t >> 6) * 2 + 1] = ss; }
    __syncthreads();
    if (t == 0) {
      const float S  = red[0] + red[2] + red[4] + red[6];
      const float SS = red[1] + red[3] + red[5] + red[7];
      const float mm = S * (1.f / 1024.f);
      const float vv = SS * (1.f / 1024.f) - mm * mm;
      smu = mm; srs = rsqrtf(vv + 1e-5f);
    }
    __syncthreads();
    const float mu = smu, rs = srs;
    const float4 g  = ((const float4*)ga)[t];
    const float4 bb = ((const float4*)be)[t];
    half4v y;
    y[0] = (_Float16)((x.x - mu) * rs * g.x + bb.x);
    y[1] = (_Float16)((x.y - mu) * rs * g.y + bb.y);
    y[2] = (_Float16)((x.z - mu) * rs * g.z + bb.z);
    y[3] = (_Float16)((x.w - mu) * rs * g.w + bb.w);
    if (is_text) {
      ((half4v*)(Tout + (size_t)row * 1024))[t] = y;
    } else {
      half4v yr;
      yr[0] = (_Float16)x.x; yr[1] = (_Float16)x.y;
      yr[2] = (_Float16)x.z; yr[3] = (_Float16)x.w;
      ((half4v*)(Rln + (size_t)row * 1024))[t] = y;
      ((half4v*)(Rraw + (size_t)row * 1024))[t] = yr;
    }
  } else {  // mask detect
    __shared__ int sany;
    if (t == 0) sany = 0;
    __syncthreads();
    int any = 0;
    for (int i = t; i < 8 * 512; i += 256)
      if ((i & 3) != 0 && mask[i] != 0) any = 1;
    if (any) sany = 1;
    __syncthreads();
    if (t == 0) *flag = sany;  // 1 => uint8, 0 => int32
  }
}

// ---------------------------------------------------------------------------
// BIG GEMM for M=16384 shapes: 256x256 tile, 512 threads, 8 waves, T4
// counted-vmcnt pipeline (4 bufs, lookahead-2), T2 swizzle, XCD swizzle,
// T5 setprio. Best-measured configuration (r16: 202.5 us total).
// EPI 0: fp16 out scaled by SC_L2E (q path: softmax scale*log2e folded here).
// EPI 1: fp32 out + resid + bias.
// ---------------------------------------------------------------------------
template <int EPI>
__global__ __launch_bounds__(512) void hgemm_big(
    const _Float16* __restrict__ A, const _Float16* __restrict__ W,
    void* __restrict__ Yv, const float* __restrict__ bias,
    const float* __restrict__ resid) {
  __shared__ _Float16 As[32768];  // 4 bufs x [256][32]
  __shared__ _Float16 Bs[32768];
  const int tid = threadIdx.x;
  const int wg = blockIdx.x;                 // 256 wgs
  const int bm = (wg & 7) * 8 + (wg >> 5);   // XCD owns 8 consecutive bm
  const int bn = (wg >> 3) & 3;              // bn fastest within XCD
  const int wid = tid >> 6, lane = tid & 63;
  const int wr = wid >> 2, wc = wid & 3;     // 2M x 4N waves
  const int l15 = lane & 15, lg = lane >> 4;

  const int c0 = tid, c1 = tid + 512;
  const int sc0 = ((c0 & 3) ^ ((c0 >> 3) & 3)) * 8;
  const int sc1 = ((c1 & 3) ^ ((c1 >> 3) & 3)) * 8;
  const _Float16* Ag0 = A + (size_t)(bm * 256 + (c0 >> 2)) * 1024 + sc0;
  const _Float16* Ag1 = A + (size_t)(bm * 256 + (c1 >> 2)) * 1024 + sc1;
  const _Float16* Bg0 = W + (size_t)(bn * 256 + (c0 >> 2)) * 1024 + sc0;
  const _Float16* Bg1 = W + (size_t)(bn * 256 + (c1 >> 2)) * 1024 + sc1;
  _Float16* Asl0 = &As[wid * 512];
  _Float16* Asl1 = &As[4096 + wid * 512];
  _Float16* Bsl0 = &Bs[wid * 512];
  _Float16* Bsl1 = &Bs[4096 + wid * 512];

  auto stage = [&](int tk, int bi) {
    const int off = tk * 32;
    gload_lds16(Ag0 + off, Asl0 + bi * 8192);
    gload_lds16(Ag1 + off, Asl1 + bi * 8192);
    gload_lds16(Bg0 + off, Bsl0 + bi * 8192);
    gload_lds16(Bg1 + off, Bsl1 + bi * 8192);
  };

  f32x4 acc[8][4] = {};
  auto compute = [&](int t) {
    const _Float16* Ab = &As[(t & 3) * 8192];
    const _Float16* Bb = &Bs[(t & 3) * 8192];
    half8v a[8], b[4];
#pragma unroll
    for (int m = 0; m < 8; m++) {
      const int row = wr * 128 + m * 16 + l15;
      a[m] = *(const half8v*)&Ab[SWZ_OFF(row, lg)];
    }
#pragma unroll
    for (int n = 0; n < 4; n++) {
      const int row = wc * 64 + n * 16 + l15;
      b[n] = *(const half8v*)&Bb[SWZ_OFF(row, lg)];
    }
    __builtin_amdgcn_s_setprio(1);
#pragma unroll
    for (int m = 0; m < 8; m++)
#pragma unroll
      for (int n = 0; n < 4; n++)
        acc[m][n] = __builtin_amdgcn_mfma_f32_16x16x32_f16(a[m], b[n], acc[m][n], 0, 0, 0);
    __builtin_amdgcn_s_setprio(0);
  };

  stage(0, 0);
  stage(1, 1);
  for (int t = 0; t < 30; ++t) {
    stage(t + 2, (t + 2) & 3);
    asm volatile("s_waitcnt vmcnt(8)" ::: "memory");
    __builtin_amdgcn_sched_barrier(0);
    __builtin_amdgcn_s_barrier();
    compute(t);
  }
  asm volatile("s_waitcnt vmcnt(4)" ::: "memory");
  __builtin_amdgcn_sched_barrier(0);
  __builtin_amdgcn_s_barrier();
  compute(30);
  asm volatile("s_waitcnt vmcnt(0)" ::: "memory");
  __builtin_amdgcn_sched_barrier(0);
  __builtin_amdgcn_s_barrier();
  compute(31);

  if (EPI == 0) {
    _Float16* Y = (_Float16*)Yv;
#pragma unroll
    for (int m = 0; m < 8; m++) {
      const int gr0 = bm * 256 + wr * 128 + m * 16 + lg * 4;
#pragma unroll
      for (int n = 0; n < 4; n++) {
        const int gc = bn * 256 + wc * 64 + n * 16 + l15;
#pragma unroll
        for (int r = 0; r < 4; r++)
          Y[(size_t)(gr0 + r) * 1024 + gc] = (_Float16)(acc[m][n][r] * SC_L2E);
      }
    }
  } else {
    float* Y = (float*)Yv;
#pragma unroll
    for (int m = 0; m < 8; m++) {
      const int gr0 = bm * 256 + wr * 128 + m * 16 + lg * 4;
#pragma unroll
      for (int n = 0; n < 4; n++) {
        const int gc = bn * 256 + wc * 64 + n * 16 + l15;
        const float bv = bias[gc];
#pragma unroll
        for (int r = 0; r < 4; r++)
          Y[(size_t)(gr0 + r) * 1024 + gc] =
              acc[m][n][r] + bv + resid[(size_t)(gr0 + r) * 1024 + gc];
      }
    }
  }
}

// ---------------------------------------------------------------------------
// Fused K and V projection GEMMs (T4 pipeline + T2 swizzle + T5 setprio).
// z=0: LN(regions)@Wk -> k16 row-major; z=1: regions@Wv -> vT transposed.
// ---------------------------------------------------------------------------
__global__ __launch_bounds__(256) void hgemm_kv(
    const _Float16* __restrict__ Aln, const _Float16* __restrict__ Araw,
    const _Float16* __restrict__ Wk, const _Float16* __restrict__ Wv,
    _Float16* __restrict__ Yk, _Float16* __restrict__ YvT) {
  __shared__ _Float16 As[16384];
  __shared__ _Float16 Bs[16384];
  const int z = blockIdx.z;
  const _Float16* A = z ? Araw : Aln;
  const _Float16* W = z ? Wv : Wk;
  const int tid = threadIdx.x;
  const int bm = blockIdx.x, bn = blockIdx.y;
  const int wid = tid >> 6, lane = tid & 63;
  const int wr = wid >> 1, wc = wid & 1;
  const int l15 = lane & 15, lg = lane >> 4;

  const int c0 = tid, c1 = tid + 256;
  const int sc0 = ((c0 & 3) ^ ((c0 >> 3) & 3)) * 8;
  const int sc1 = ((c1 & 3) ^ ((c1 >> 3) & 3)) * 8;
  const _Float16* Ag0 = A + (size_t)(bm * 128 + (c0 >> 2)) * 1024 + sc0;
  const _Float16* Ag1 = A + (size_t)(bm * 128 + (c1 >> 2)) * 1024 + sc1;
  const _Float16* Bg0 = W + (size_t)(bn * 128 + (c0 >> 2)) * 1024 + sc0;
  const _Float16* Bg1 = W + (size_t)(bn * 128 + (c1 >> 2)) * 1024 + sc1;
  _Float16* Asl = &As[wid * 512];
  _Float16* Bsl = &Bs[wid * 512];

  auto stage = [&](int tk, int bi) {
    const int off = tk * 32;
    gload_lds16(Ag0 + off, Asl + bi * 4096);
    gload_lds16(Ag1 + off, Asl + bi * 4096 + 2048);
    gload_lds16(Bg0 + off, Bsl + bi * 4096);
    gload_lds16(Bg1 + off, Bsl + bi * 4096 + 2048);
  };

  f32x4 acc[4][4] = {};
  auto compute = [&](int t) {
    const _Float16* Ab = &As[(t & 3) * 4096];
    const _Float16* Bb = &Bs[(t & 3) * 4096];
    half8v a[4], b[4];
#pragma unroll
    for (int m = 0; m < 4; m++) {
      const int row = wr * 64 + m * 16 + l15;
      a[m] = *(const half8v*)&Ab[SWZ_OFF(row, lg)];
    }
#pragma unroll
    for (int n = 0; n < 4; n++) {
      const int row = wc * 64 + n * 16 + l15;
      b[n] = *(const half8v*)&Bb[SWZ_OFF(row, lg)];
    }
    __builtin_amdgcn_s_setprio(1);
#pragma unroll
    for (int m = 0; m < 4; m++)
#pragma unroll
      for (int n = 0; n < 4; n++)
        acc[m][n] = __builtin_amdgcn_mfma_f32_16x16x32_f16(a[m], b[n], acc[m][n], 0, 0, 0);
    __builtin_amdgcn_s_setprio(0);
  };

  stage(0, 0);
  stage(1, 1);
  for (int t = 0; t < 30; ++t) {
    stage(t + 2, (t + 2) & 3);
    asm volatile("s_waitcnt vmcnt(8)" ::: "memory");
    __builtin_amdgcn_sched_barrier(0);
    __builtin_amdgcn_s_barrier();
    compute(t);
  }
  asm volatile("s_waitcnt vmcnt(4)" ::: "memory");
  __builtin_amdgcn_sched_barrier(0);
  __builtin_amdgcn_s_barrier();
  compute(30);
  asm volatile("s_waitcnt vmcnt(0)" ::: "memory");
  __builtin_amdgcn_sched_barrier(0);
  __builtin_amdgcn_s_barrier();
  compute(31);

  if (z == 0) {
#pragma unroll
    for (int m = 0; m < 4; m++) {
      const int gr0 = bm * 128 + wr * 64 + m * 16 + lg * 4;
#pragma unroll
      for (int n = 0; n < 4; n++) {
        const int gc = bn * 128 + wc * 64 + n * 16 + l15;
#pragma unroll
        for (int r = 0; r < 4; r++)
          Yk[(size_t)(gr0 + r) * 1024 + gc] = (_Float16)acc[m][n][r];
      }
    }
  } else {
#pragma unroll
    for (int m = 0; m < 4; m++) {
      const int gr0 = bm * 128 + wr * 64 + m * 16 + lg * 4;
#pragma unroll
      for (int n = 0; n < 4; n++) {
        const int gc = bn * 128 + wc * 64 + n * 16 + l15;
#pragma unroll
        for (int r = 0; r < 4; r++) {
          const int tokenv = gr0 + r;
          YvT[(size_t)((tokenv >> 9) * 1024 + gc) * 512 + (tokenv & 511)] =
              (_Float16)acc[m][n][r];
        }
      }
    }
  }
}

// ---------------------------------------------------------------------------
// MFMA flash attention v9 (frozen): T1 XCD swizzle (XCD x owns batch b=x ->
// K/V 4MB fits private L2; FETCH 82->24MB) + mask-as-MFMA-C-input +
// pre-scaled Q; defer-max; permlane PV assembly; swizzled LDS epilogue.
// ---------------------------------------------------------------------------
__global__ __launch_bounds__(256, 4) void attn_v9(
    const _Float16* __restrict__ q, const _Float16* __restrict__ kk,
    const _Float16* __restrict__ vT, const void* __restrict__ maskp,
    const int* __restrict__ flag, _Float16* __restrict__ ctx) {
  __shared__ union SMem {
    struct { _Float16 K[2][2][2048]; _Float16 V[2][2][2048]; } s;  // 32 KB
    _Float16 Ot[4][2048];                                          // 16 KB
  } sm;
  __shared__ float Msk[512];

  const int bid = (blockIdx.x & 7) * 256 + (blockIdx.x >> 3);
  const int qt = bid & 15, hh = (bid >> 4) & 15, b = bid >> 8;
  const int tid = threadIdx.x;
  const int wid = tid >> 6, lane = tid & 63;
  const int l31 = lane & 31;
  const int hi  = lane >> 5;

  {
    const bool mu8 = (*flag != 0);
    const unsigned char* m8 = (const unsigned char*)maskp;
    const int* m32 = (const int*)maskp;
    for (int i = tid; i < 512; i += 256) {
      const bool mv = mu8 ? (m8[b * 512 + i] != 0) : (m32[b * 512 + i] != 0);
      Msk[i] = mv ? 0.f : -__builtin_inff();
    }
  }

  const _Float16* kb = kk + (size_t)b * 512 * 1024 + hh * 64;
  const _Float16* vb = vT + (size_t)(b * 1024 + hh * 64) * 512;

  const int krow = wid * 8 + (lane >> 3);
  const int kchk = (lane & 7) ^ ((lane >> 3) & 7);
  const _Float16* ksrc = kb + (size_t)krow * 1024 + kchk * 8;
  const int vrow = wid * 16 + (lane >> 2);
  const int vchk = (lane & 3) ^ ((lane >> 3) & 3);
  const _Float16* vsrc = vb + (size_t)vrow * 512 + vchk * 8;

  const int tok0 = b * 2048 + qt * 128 + wid * 32;
  half8v bq[4];
#pragma unroll
  for (int kg = 0; kg < 4; kg++)
    bq[kg] = *(const half8v*)(q + (size_t)(tok0 + l31) * 1024 + hh * 64 + kg * 16 + hi * 8);

  float m_s = -1e30f, l_s = 0.f;
  f32x16 ot0 = {}, ot1 = {};

  auto stage = [&](int step, int bi) {
#pragma unroll
    for (int sub = 0; sub < 2; sub++) {
      const int tile = step * 2 + sub;
      gload_lds16(ksrc + (size_t)tile * 32 * 1024, &sm.s.K[bi][sub][wid * 512]);
      gload_lds16(vsrc + tile * 32, &sm.s.V[bi][sub][wid * 512]);
    }
  };

  stage(0, 0);
  __syncthreads();  // drains vmcnt; also covers Msk writes

  int buf = 0;
  for (int step = 0; step < 8; step++) {
    if (step < 7) stage(step + 1, buf ^ 1);

#pragma unroll
    for (int sub = 0; sub < 2; sub++) {
      const int nt = step * 2 + sub;

      half8v ak[4];
#pragma unroll
      for (int kg = 0; kg < 4; kg++)
        ak[kg] = *(const half8v*)&sm.s.K[buf][sub][l31 * 64 + ((kg * 2 + hi) ^ (l31 & 7)) * 8];

      f32x16 st;
#pragma unroll
      for (int j = 0; j < 4; j++) {
        const float4 mk = *(const float4*)&Msk[nt * 32 + j * 8 + hi * 4];
        st[4 * j + 0] = mk.x;
        st[4 * j + 1] = mk.y;
        st[4 * j + 2] = mk.z;
        st[4 * j + 3] = mk.w;
      }
#pragma unroll
      for (int kg = 0; kg < 4; kg++)
        st = __builtin_amdgcn_mfma_f32_32x32x16_f16(ak[kg], bq[kg], st, 0, 0, 0);

      half8v av[2][2];
#pragma unroll
      for (int dv = 0; dv < 2; dv++)
#pragma unroll
        for (int kc = 0; kc < 2; kc++)
          av[dv][kc] = *(const half8v*)&sm.s.V[buf][sub][(dv * 32 + l31) * 32 +
                                                        ((kc * 2 + hi) ^ ((l31 >> 1) & 3)) * 8];

      const float t0 = FMAX3(st[0], st[1], st[2]);
      const float t1 = FMAX3(st[3], st[4], st[5]);
      const float t2 = FMAX3(st[6], st[7], st[8]);
      const float t3 = FMAX3(st[9], st[10], st[11]);
      const float t4 = FMAX3(st[12], st[13], st[14]);
      float tmax = fmaxf(FMAX3(t0, t1, t2), FMAX3(t3, t4, st[15]));
      tmax = fmaxf(tmax, __shfl_xor(tmax, 32, 64));

      if (__any(tmax > m_s + 8.f)) {
        const float mnew = fmaxf(m_s, tmax);
        const float corr = EXP2(m_s - mnew);
        m_s = mnew;
        l_s *= corr;
#pragma unroll
        for (int r = 0; r < 16; r++) { ot0[r] *= corr; ot1[r] *= corr; }
      }

      float p[16];
#pragma unroll
      for (int r = 0; r < 16; r++) p[r] = EXP2(st[r] - m_s);  // bounded by 2^8

      unsigned int pk[4][2];
#pragma unroll
      for (int j = 0; j < 4; j++)
#pragma unroll
        for (int pp = 0; pp < 2; pp++)
          pk[j][pp] = __builtin_bit_cast(
              unsigned int, CVTPK(p[4 * j + 2 * pp], p[4 * j + 2 * pp + 1]));

      {
#pragma unroll
        for (int r = 0; r < 8; r++) p[r] += p[r + 8];
#pragma unroll
        for (int r = 0; r < 4; r++) p[r] += p[r + 4];
        float ts = (p[0] + p[1]) + (p[2] + p[3]);
        ts += __shfl_xor(ts, 32, 64);
        l_s += ts;
      }

      half8v pb[2];
#pragma unroll
      for (int kc = 0; kc < 2; kc++) {
        unsigned int x0 = pk[2 * kc][0], x1 = pk[2 * kc][1];
        unsigned int y0 = pk[2 * kc + 1][0], y1 = pk[2 * kc + 1][1];
        asm("v_permlane32_swap_b32 %0, %1" : "+v"(x0), "+v"(y0));
        asm("v_permlane32_swap_b32 %0, %1" : "+v"(x1), "+v"(y1));
        uint4 u; u.x = x0; u.y = x1; u.z = y0; u.w = y1;
        pb[kc] = __builtin_bit_cast(half8v, u);
      }

      ot0 = __builtin_amdgcn_mfma_f32_32x32x16_f16(av[0][0], pb[0], ot0, 0, 0, 0);
      ot0 = __builtin_amdgcn_mfma_f32_32x32x16_f16(av[0][1], pb[1], ot0, 0, 0, 0);
      ot1 = __builtin_amdgcn_mfma_f32_32x32x16_f16(av[1][0], pb[0], ot1, 0, 0, 0);
      ot1 = __builtin_amdgcn_mfma_f32_32x32x16_f16(av[1][1], pb[1], ot1, 0, 0, 0);
    }

    __syncthreads();
    buf ^= 1;
  }

  const float inv = (l_s > 0.f) ? (1.f / l_s) : 0.f;
#pragma unroll
  for (int dv = 0; dv < 2; dv++) {
#pragma unroll
    for (int j = 0; j < 4; j++)
#pragma unroll
      for (int pp = 0; pp < 2; pp++) {
        const int r = 4 * j + 2 * pp;
        const float v0 = (dv ? ot1[r] : ot0[r]) * inv;
        const float v1 = (dv ? ot1[r + 1] : ot0[r + 1]) * inv;
        const int col = dv * 32 + 8 * j + 4 * hi + 2 * pp;
        const int pos = l31 * 64 + (col ^ (8 * (l31 & 7)));
        *(unsigned int*)&sm.Ot[wid][pos] = __builtin_bit_cast(unsigned int, CVTPK(v0, v1));
      }
  }
  __syncthreads();
#pragma unroll
  for (int qh = 0; qh < 2; qh++)
#pragma unroll
    for (int k2 = 0; k2 < 2; k2++) {
      const int qq = qh * 16 + (lane >> 2);
      const int c  = (lane & 3) * 8 + k2 * 32;
      const half8v val = *(const half8v*)&sm.Ot[wid][qq * 64 + (c ^ (8 * (qq & 7)))];
      *(half8v*)(ctx + (size_t)(tok0 + qq) * 1024 + hh * 64 + c) = val;
    }
}

// ---------------------------------------------------------------------------
extern "C" void kernel_launch(void* const* d_in, const int* in_sizes, int n_in,
                              void* d_out, int out_size, void* d_ws, size_t ws_size,
                              hipStream_t stream) {
  const float* text    = (const float*)d_in[0];
  const float* regions = (const float*)d_in[1];
  const void*  mask    = d_in[2];
  const float* Wq      = (const float*)d_in[3];
  const float* Wk      = (const float*)d_in[4];
  const float* Wv      = (const float*)d_in[5];
  const float* Wo      = (const float*)d_in[6];
  const float* bo      = (const float*)d_in[7];
  const float* gq      = (const float*)d_in[8];
  const float* bq      = (const float*)d_in[9];
  const float* gkv     = (const float*)d_in[10];
  const float* bkv     = (const float*)d_in[11];

  _Float16* ws16 = (_Float16*)d_ws;
  _Float16* wq16 = ws16;                   // 4 weights contiguous, 1M halves each
  _Float16* wk16 = wq16 + 1048576;
  _Float16* wv16 = wk16 + 1048576;
  _Float16* wo16 = wv16 + 1048576;
  _Float16* at16 = wo16 + 1048576;         // 16.7M (LN text)
  _Float16* q16  = at16 + 16777216;        // 16.7M (doubles as ctx)
  _Float16* k16  = q16 + 16777216;         // 4.2M
  _Float16* vTb  = k16 + 4194304;          // 4.2M  (V^T: [b*1024 + col][512])
  int* flag = (int*)(vTb + 4194304);
  _Float16* rln16  = (_Float16*)(flag + 16);   // 4.2M (regions LN)
  _Float16* rraw16 = rln16 + 4194304;          // 4.2M (regions raw)

  // ALL independent prep in one launch (22529 blocks)
  prep_all_kernel<<<22529, 256, 0, stream>>>(
      Wq, Wk, Wv, Wo, wq16, text, gq, bq, at16,
      regions, gkv, bkv, rln16, rraw16,
      (const unsigned char*)mask, flag);

  // q = (LN(text) @ Wq^T) * (0.125*log2e)  (scale folded into epilogue)
  hgemm_big<0><<<256, 512, 0, stream>>>(at16, wq16, q16, nullptr, nullptr);

  // k = LN(regions) @ Wk^T ; vT = (regions @ Wv^T)^T  (fused, grid.z)
  hgemm_kv<<<dim3(32, 8, 2), 256, 0, stream>>>(rln16, rraw16, wk16, wv16, k16, vTb);

  // attention (ctx overwrites q16; block-private rows/cols)
  attn_v9<<<2048, 256, 0, stream>>>(q16, k16, vTb, mask, flag, q16);

  // out = text + ctx @ Wo^T + bo
  hgemm_big<1><<<256, 512, 0, stream>>>(q16, wo16, d_out, bo, text);
}